// Round 2
// baseline (1255.498 us; speedup 1.0000x reference)
//
#include <hip/hip_runtime.h>
#include <math.h>

#define H_  192
#define W_  192
#define HW_ (192 * 192)
#define B_  2
#define C_  64

// ---------------------------------------------------------------------------
// wave-wide butterfly sum (64 lanes) — every lane ends with the total
// ---------------------------------------------------------------------------
__device__ __forceinline__ float wave_sum(float v) {
    #pragma unroll
    for (int off = 32; off > 0; off >>= 1)
        v += __shfl_xor(v, off, 64);
    return v;
}

// ---------------------------------------------------------------------------
// bilinear sample with zero padding outside image (matches reference exactly:
// corner weight zeroed when corner is out of bounds, gather index clamped)
// ---------------------------------------------------------------------------
__device__ __forceinline__ float bilin(const float* __restrict__ pl, float ys, float xs) {
    float y0 = floorf(ys), x0 = floorf(xs);
    float fy = ys - y0, fx = xs - x0;
    int iy = (int)y0, ix = (int)x0;
    float acc = 0.f;
    #pragma unroll
    for (int dy = 0; dy < 2; ++dy) {
        #pragma unroll
        for (int dx = 0; dx < 2; ++dx) {
            int yy = iy + dy, xx = ix + dx;
            float wgt = (dy ? fy : 1.f - fy) * (dx ? fx : 1.f - fx);
            bool valid = (yy >= 0) && (yy < H_) && (xx >= 0) && (xx < W_);
            int yc = min(max(yy, 0), H_ - 1);
            int xc = min(max(xx, 0), W_ - 1);
            float g = pl[yc * W_ + xc];
            acc += valid ? wgt * g : 0.f;
        }
    }
    return acc;
}

// ---------------------------------------------------------------------------
// weight transpose: OIHW -> [ci*9+ky*3+kx][co]  (one-shot, tiny)
// ---------------------------------------------------------------------------
__global__ __launch_bounds__(256) void transpose_w(
    const float* __restrict__ w1, const float* __restrict__ w2,
    const float* __restrict__ wom,
    float* __restrict__ t1, float* __restrict__ t2, float* __restrict__ tom)
{
    int idx = blockIdx.x * 256 + threadIdx.x;
    if (idx < 64 * 1152) {                       // w1: (64, 128, 3, 3)
        int co = idx / 1152, r = idx - co * 1152;
        t1[r * 64 + co] = w1[idx];
        return;
    }
    idx -= 64 * 1152;
    if (idx < 64 * 576) {                        // w2: (64, 64, 3, 3)
        int co = idx / 576, r = idx - co * 576;
        t2[r * 64 + co] = w2[idx];
        return;
    }
    idx -= 64 * 576;
    if (idx < 216 * 576) {                       // w_om: (216, 64, 3, 3)
        int co = idx / 576, r = idx - co * 576;
        tom[r * 216 + co] = wom[idx];
    }
}

// ---------------------------------------------------------------------------
// direct 3x3 SAME conv, NCHW.
// block = 256 threads: 64-pixel row strip (px = tid&63) x 4 co-groups.
// input staged per-8-ci-chunk in LDS (8*3*66 floats); weights read as
// wave-uniform contiguous rows -> scalar loads.
// in = in0 channels [0,64) and in1 channels [64,CIN) (conv1 concat trick).
// ---------------------------------------------------------------------------
template<int CIN, int COUT, bool LRELU>
__global__ __launch_bounds__(256) void conv3_k(
    const float* __restrict__ in0, const float* __restrict__ in1,
    const float* __restrict__ wT, const float* __restrict__ bias,
    float* __restrict__ out)
{
    constexpr int CO_T = COUT / 4;
    constexpr int SM_N = 8 * 3 * 66;
    __shared__ float smem[SM_N];
    const int tid = threadIdx.x;
    const int px  = tid & 63;
    const int cg  = tid >> 6;
    const int j0  = blockIdx.x * 64;
    const int i0  = blockIdx.y;
    const int b   = blockIdx.z;
    const int co_base = __builtin_amdgcn_readfirstlane(cg * CO_T);

    float acc[CO_T];
    #pragma unroll
    for (int c = 0; c < CO_T; ++c) acc[c] = 0.f;

    const float* wb = wT + co_base;

    for (int cb = 0; cb < CIN; cb += 8) {
        __syncthreads();
        for (int idx = tid; idx < SM_N; idx += 256) {
            int ci  = idx / 198;
            int rem = idx - ci * 198;
            int r   = rem / 66;
            int cc  = rem - r * 66;
            int gci = cb + ci;
            const float* src = (gci < 64)
                ? (in0 + (size_t)(b * 64 + gci) * HW_)
                : (in1 + (size_t)(b * 64 + gci - 64) * HW_);
            int y = i0 + r - 1;
            int x = j0 + cc - 1;
            float v = 0.f;
            if (y >= 0 && y < H_ && x >= 0 && x < W_) v = src[y * W_ + x];
            smem[idx] = v;
        }
        __syncthreads();
        for (int ci = 0; ci < 8; ++ci) {
            #pragma unroll
            for (int ky = 0; ky < 3; ++ky) {
                #pragma unroll
                for (int kx = 0; kx < 3; ++kx) {
                    float v = smem[(ci * 3 + ky) * 66 + px + kx];
                    const float* wrow = wb + (size_t)((cb + ci) * 9 + ky * 3 + kx) * COUT;
                    #pragma unroll
                    for (int c = 0; c < CO_T; ++c)
                        acc[c] = fmaf(v, wrow[c], acc[c]);
                }
            }
        }
    }
    const int p = i0 * W_ + j0 + px;
    #pragma unroll
    for (int c = 0; c < CO_T; ++c) {
        float v = acc[c] + bias[co_base + c];
        if (LRELU) v = (v >= 0.f) ? v : 0.1f * v;
        out[(size_t)(b * COUT + co_base + c) * HW_ + p] = v;
    }
}

// ---------------------------------------------------------------------------
// fused deformable sampling + top-2 attention.
// one 64-lane wave per pixel; lane = channel c; g = c>>3.
// key sampled for all 9 taps (kept in regs), rel via butterfly reductions,
// redundant per-lane top-2 (lax.top_k tie semantics), value sampled ONLY for
// the 2 selected taps.
// ---------------------------------------------------------------------------
__global__ __launch_bounds__(256) void sampler_k(
    const float* __restrict__ query, const float* __restrict__ key,
    const float* __restrict__ value, const float* __restrict__ om,
    float* __restrict__ out_w, float* __restrict__ out_v)
{
    const int lane = threadIdx.x & 63;
    const int wid  = threadIdx.x >> 6;
    const int P    = blockIdx.x * 4 + wid;          // 0 .. B*HW-1
    const int b    = (P >= HW_) ? 1 : 0;
    const int p    = P - b * HW_;
    const int i    = p / W_;
    const int j    = p - i * W_;
    const int c    = lane;
    const int g    = lane >> 3;

    const size_t bc = (size_t)(b * C_ + c) * HW_;
    const float qc  = query[bc + p];
    const float* omb = om + (size_t)b * (216 * HW_) + p;

    float offy[9], offx[9], mk[9];
    #pragma unroll
    for (int n = 0; n < 9; ++n) {
        offy[n] = omb[(size_t)(g * 9 + n) * HW_];
        offx[n] = omb[(size_t)(72 + g * 9 + n) * HW_];
        float mv = omb[(size_t)(144 + g * 9 + n) * HW_];
        mk[n] = 1.f / (1.f + expf(-mv));
    }

    const float* kpl = key + bc;
    float kv[9], rel[9];
    #pragma unroll
    for (int n = 0; n < 9; ++n) {
        float ys = (float)i + (float)(n / 3 - 1) + offy[n];
        float xs = (float)j + (float)(n % 3 - 1) + offx[n];
        kv[n]  = bilin(kpl, ys, xs) * mk[n];
        rel[n] = wave_sum(kv[n] * qc);
    }

    // top-2 with lax.top_k tie semantics (first occurrence of max wins)
    int n0 = 0; float v0 = rel[0];
    #pragma unroll
    for (int n = 1; n < 9; ++n) { if (rel[n] > v0) { v0 = rel[n]; n0 = n; } }
    int n1 = -1; float v1 = -1e30f;
    #pragma unroll
    for (int n = 0; n < 9; ++n) { if (n != n0 && rel[n] > v1) { v1 = rel[n]; n1 = n; } }

    // softmax over (v0, v1), v0 >= v1
    float e1  = expf(v1 - v0);
    float inv = 1.f / (1.f + e1);
    float c0 = inv, c1 = e1 * inv;

    // select per-lane registers for n0 / n1 (static unroll -> cndmask chains)
    float kv0 = 0, kv1 = 0, oy0 = 0, ox0 = 0, m0 = 0, oy1 = 0, ox1 = 0, m1 = 0;
    #pragma unroll
    for (int n = 0; n < 9; ++n) {
        if (n == n0) { kv0 = kv[n]; oy0 = offy[n]; ox0 = offx[n]; m0 = mk[n]; }
        if (n == n1) { kv1 = kv[n]; oy1 = offy[n]; ox1 = offx[n]; m1 = mk[n]; }
    }

    float kupd = c0 * kv0 + c1 * kv1;
    float wsum = wave_sum(qc * kupd);
    if (lane == 0) out_w[(size_t)b * HW_ + p] = wsum;

    const float* vpl = value + bc;
    float ys0 = (float)i + (float)(n0 / 3 - 1) + oy0;
    float xs0 = (float)j + (float)(n0 % 3 - 1) + ox0;
    float ys1 = (float)i + (float)(n1 / 3 - 1) + oy1;
    float xs1 = (float)j + (float)(n1 % 3 - 1) + ox1;
    float vv0 = bilin(vpl, ys0, xs0) * m0;
    float vv1 = bilin(vpl, ys1, xs1) * m1;
    out_v[bc + p] = c0 * vv0 + c1 * vv1;
}

// ---------------------------------------------------------------------------
extern "C" void kernel_launch(void* const* d_in, const int* in_sizes, int n_in,
                              void* d_out, int out_size, void* d_ws, size_t ws_size,
                              hipStream_t stream)
{
    const float* query = (const float*)d_in[0];
    const float* key   = (const float*)d_in[1];
    const float* value = (const float*)d_in[2];
    const float* w1    = (const float*)d_in[3];
    const float* b1    = (const float*)d_in[4];
    const float* w2    = (const float*)d_in[5];
    const float* b2    = (const float*)d_in[6];
    const float* wom   = (const float*)d_in[7];
    const float* bom   = (const float*)d_in[8];
    float* out = (float*)d_out;

    // workspace layout (floats): feat1 | feat2 | om | wT1 | wT2 | wTom
    float* ws    = (float*)d_ws;
    float* feat1 = ws;                                   // B*64*HW
    float* feat2 = feat1 + (size_t)B_ * 64 * HW_;        // B*64*HW
    float* ombuf = feat2 + (size_t)B_ * 64 * HW_;        // B*216*HW
    float* t1    = ombuf + (size_t)B_ * 216 * HW_;       // 1152*64
    float* t2    = t1 + 1152 * 64;                       // 576*64
    float* tom   = t2 + 576 * 64;                        // 576*216

    transpose_w<<<918, 256, 0, stream>>>(w1, w2, wom, t1, t2, tom);

    dim3 cgrid(W_ / 64, H_, B_);
    conv3_k<128, 64, true ><<<cgrid, 256, 0, stream>>>(query, key,  t1,  b1,  feat1);
    conv3_k< 64, 64, true ><<<cgrid, 256, 0, stream>>>(feat1, feat1, t2,  b2,  feat2);
    conv3_k< 64, 216, false><<<cgrid, 256, 0, stream>>>(feat2, feat2, tom, bom, ombuf);

    float* out_w = out;
    float* out_v = out + (size_t)B_ * HW_;
    sampler_k<<<(B_ * HW_) / 4, 256, 0, stream>>>(query, key, value, ombuf, out_w, out_v);
}

// Round 3
// 812.777 us; speedup vs baseline: 1.5447x; 1.5447x over previous
//
#include <hip/hip_runtime.h>
#include <math.h>

#define H_  192
#define W_  192
#define HW_ (192 * 192)
#define B_  2
#define C_  64

// ---------------------------------------------------------------------------
// wave-wide butterfly sum (64 lanes) — every lane ends with the total
// ---------------------------------------------------------------------------
__device__ __forceinline__ float wave_sum(float v) {
    #pragma unroll
    for (int off = 32; off > 0; off >>= 1)
        v += __shfl_xor(v, off, 64);
    return v;
}

// ---------------------------------------------------------------------------
// bilinear sample from an NHWC plane ([HW][64] for one batch), channel c.
// zero padding outside image; corner weight zeroed when OOB, index clamped
// (matches reference semantics exactly).
// ---------------------------------------------------------------------------
__device__ __forceinline__ float bilin_nhwc(const float* __restrict__ pl,
                                            float ys, float xs, int c) {
    float y0 = floorf(ys), x0 = floorf(xs);
    float fy = ys - y0, fx = xs - x0;
    int iy = (int)y0, ix = (int)x0;
    float acc = 0.f;
    #pragma unroll
    for (int dy = 0; dy < 2; ++dy) {
        #pragma unroll
        for (int dx = 0; dx < 2; ++dx) {
            int yy = iy + dy, xx = ix + dx;
            float wgt = (dy ? fy : 1.f - fy) * (dx ? fx : 1.f - fx);
            bool valid = (yy >= 0) && (yy < H_) && (xx >= 0) && (xx < W_);
            int yc = min(max(yy, 0), H_ - 1);
            int xc = min(max(xx, 0), W_ - 1);
            float g = pl[(size_t)(yc * W_ + xc) * 64 + c];   // coalesced across lanes
            acc += valid ? wgt * g : 0.f;
        }
    }
    return acc;
}

// ---------------------------------------------------------------------------
// weight transpose: OIHW -> [ci*9+ky*3+kx][co]  (one-shot, tiny)
// ---------------------------------------------------------------------------
__global__ __launch_bounds__(256) void transpose_w(
    const float* __restrict__ w1, const float* __restrict__ w2,
    const float* __restrict__ wom,
    float* __restrict__ t1, float* __restrict__ t2, float* __restrict__ tom)
{
    int idx = blockIdx.x * 256 + threadIdx.x;
    if (idx < 64 * 1152) {                       // w1: (64, 128, 3, 3)
        int co = idx / 1152, r = idx - co * 1152;
        t1[r * 64 + co] = w1[idx];
        return;
    }
    idx -= 64 * 1152;
    if (idx < 64 * 576) {                        // w2: (64, 64, 3, 3)
        int co = idx / 576, r = idx - co * 576;
        t2[r * 64 + co] = w2[idx];
        return;
    }
    idx -= 64 * 576;
    if (idx < 216 * 576) {                       // w_om: (216, 64, 3, 3)
        int co = idx / 576, r = idx - co * 576;
        tom[r * 216 + co] = wom[idx];
    }
}

// ---------------------------------------------------------------------------
// NCHW -> NHWC transpose for key/value, 64-pixel x 64-channel LDS tiles.
// Both global phases fully coalesced; LDS padded [64][65] -> conflict-free.
// blockIdx.z selects (key->kT) or (value->vT).
// ---------------------------------------------------------------------------
__global__ __launch_bounds__(256) void nchw_to_nhwc(
    const float* __restrict__ key, const float* __restrict__ value,
    float* __restrict__ kT, float* __restrict__ vT)
{
    __shared__ float sm[64][65];
    const int tid = threadIdx.x;
    const int p0  = blockIdx.x * 64;
    const int b   = blockIdx.y;
    const float* src = blockIdx.z ? value : key;
    float*       dst = blockIdx.z ? vT    : kT;

    const int pp = tid & 63;
    const int r0 = tid >> 6;
    #pragma unroll
    for (int c = r0; c < 64; c += 4)              // read: coalesced along p
        sm[c][pp] = src[(size_t)(b * 64 + c) * HW_ + p0 + pp];
    __syncthreads();
    const int cc = tid & 63;
    #pragma unroll
    for (int pw = r0; pw < 64; pw += 4)           // write: coalesced along c
        dst[((size_t)b * HW_ + p0 + pw) * 64 + cc] = sm[cc][pw];
}

// ---------------------------------------------------------------------------
// direct 3x3 SAME conv, NCHW.
// block = 256 threads: 64-pixel row strip (px = tid&63) x 4 co-groups.
// input staged per-8-ci-chunk in LDS; weights read wave-uniform -> scalar.
// ---------------------------------------------------------------------------
template<int CIN, int COUT, bool LRELU>
__global__ __launch_bounds__(256) void conv3_k(
    const float* __restrict__ in0, const float* __restrict__ in1,
    const float* __restrict__ wT, const float* __restrict__ bias,
    float* __restrict__ out)
{
    constexpr int CO_T = COUT / 4;
    constexpr int SM_N = 8 * 3 * 66;
    __shared__ float smem[SM_N];
    const int tid = threadIdx.x;
    const int px  = tid & 63;
    const int cg  = tid >> 6;
    const int j0  = blockIdx.x * 64;
    const int i0  = blockIdx.y;
    const int b   = blockIdx.z;
    const int co_base = __builtin_amdgcn_readfirstlane(cg * CO_T);

    float acc[CO_T];
    #pragma unroll
    for (int c = 0; c < CO_T; ++c) acc[c] = 0.f;

    const float* wb = wT + co_base;

    for (int cb = 0; cb < CIN; cb += 8) {
        __syncthreads();
        for (int idx = tid; idx < SM_N; idx += 256) {
            int ci  = idx / 198;
            int rem = idx - ci * 198;
            int r   = rem / 66;
            int cc  = rem - r * 66;
            int gci = cb + ci;
            const float* src = (gci < 64)
                ? (in0 + (size_t)(b * 64 + gci) * HW_)
                : (in1 + (size_t)(b * 64 + gci - 64) * HW_);
            int y = i0 + r - 1;
            int x = j0 + cc - 1;
            float v = 0.f;
            if (y >= 0 && y < H_ && x >= 0 && x < W_) v = src[y * W_ + x];
            smem[idx] = v;
        }
        __syncthreads();
        for (int ci = 0; ci < 8; ++ci) {
            #pragma unroll
            for (int ky = 0; ky < 3; ++ky) {
                #pragma unroll
                for (int kx = 0; kx < 3; ++kx) {
                    float v = smem[(ci * 3 + ky) * 66 + px + kx];
                    const float* wrow = wb + (size_t)((cb + ci) * 9 + ky * 3 + kx) * COUT;
                    #pragma unroll
                    for (int c = 0; c < CO_T; ++c)
                        acc[c] = fmaf(v, wrow[c], acc[c]);
                }
            }
        }
    }
    const int p = i0 * W_ + j0 + px;
    #pragma unroll
    for (int c = 0; c < CO_T; ++c) {
        float v = acc[c] + bias[co_base + c];
        if (LRELU) v = (v >= 0.f) ? v : 0.1f * v;
        out[(size_t)(b * COUT + co_base + c) * HW_ + p] = v;
    }
}

// ---------------------------------------------------------------------------
// fused deformable sampling + top-2 attention.
// one 64-lane wave per pixel; lane = channel c; g = c>>3.
// key/value read from NHWC transposed copies -> coalesced corner gathers.
// ---------------------------------------------------------------------------
__global__ __launch_bounds__(256) void sampler_k(
    const float* __restrict__ query, const float* __restrict__ kT,
    const float* __restrict__ vT, const float* __restrict__ om,
    float* __restrict__ out_w, float* __restrict__ out_v)
{
    const int lane = threadIdx.x & 63;
    const int wid  = threadIdx.x >> 6;
    const int P    = blockIdx.x * 4 + wid;          // 0 .. B*HW-1
    const int b    = (P >= HW_) ? 1 : 0;
    const int p    = P - b * HW_;
    const int i    = p / W_;
    const int j    = p - i * W_;
    const int c    = lane;
    const int g    = lane >> 3;

    const float qc  = query[(size_t)(b * C_ + c) * HW_ + p];
    const float* omb = om + (size_t)b * (216 * HW_) + p;

    float offy[9], offx[9], mk[9];
    #pragma unroll
    for (int n = 0; n < 9; ++n) {
        offy[n] = omb[(size_t)(g * 9 + n) * HW_];
        offx[n] = omb[(size_t)(72 + g * 9 + n) * HW_];
        float mv = omb[(size_t)(144 + g * 9 + n) * HW_];
        mk[n] = 1.f / (1.f + expf(-mv));
    }

    const float* kpl = kT + (size_t)b * HW_ * 64;
    float kv[9], rel[9];
    #pragma unroll
    for (int n = 0; n < 9; ++n) {
        float ys = (float)i + (float)(n / 3 - 1) + offy[n];
        float xs = (float)j + (float)(n % 3 - 1) + offx[n];
        kv[n]  = bilin_nhwc(kpl, ys, xs, c) * mk[n];
        rel[n] = wave_sum(kv[n] * qc);
    }

    // top-2 with lax.top_k tie semantics (first occurrence of max wins)
    int n0 = 0; float v0 = rel[0];
    #pragma unroll
    for (int n = 1; n < 9; ++n) { if (rel[n] > v0) { v0 = rel[n]; n0 = n; } }
    int n1 = -1; float v1 = -1e30f;
    #pragma unroll
    for (int n = 0; n < 9; ++n) { if (n != n0 && rel[n] > v1) { v1 = rel[n]; n1 = n; } }

    // softmax over (v0, v1), v0 >= v1
    float e1  = expf(v1 - v0);
    float inv = 1.f / (1.f + e1);
    float c0 = inv, c1 = e1 * inv;

    // select per-lane registers for n0 / n1 (static unroll -> cndmask chains)
    float kv0 = 0, kv1 = 0, oy0 = 0, ox0 = 0, m0 = 0, oy1 = 0, ox1 = 0, m1 = 0;
    #pragma unroll
    for (int n = 0; n < 9; ++n) {
        if (n == n0) { kv0 = kv[n]; oy0 = offy[n]; ox0 = offx[n]; m0 = mk[n]; }
        if (n == n1) { kv1 = kv[n]; oy1 = offy[n]; ox1 = offx[n]; m1 = mk[n]; }
    }

    float kupd = c0 * kv0 + c1 * kv1;
    float wsum = wave_sum(qc * kupd);
    if (lane == 0) out_w[(size_t)b * HW_ + p] = wsum;

    const float* vpl = vT + (size_t)b * HW_ * 64;
    float ys0 = (float)i + (float)(n0 / 3 - 1) + oy0;
    float xs0 = (float)j + (float)(n0 % 3 - 1) + ox0;
    float ys1 = (float)i + (float)(n1 / 3 - 1) + oy1;
    float xs1 = (float)j + (float)(n1 % 3 - 1) + ox1;
    float vv0 = bilin_nhwc(vpl, ys0, xs0, c) * m0;
    float vv1 = bilin_nhwc(vpl, ys1, xs1, c) * m1;
    out_v[(size_t)(b * C_ + c) * HW_ + p] = c0 * vv0 + c1 * vv1;
}

// ---------------------------------------------------------------------------
extern "C" void kernel_launch(void* const* d_in, const int* in_sizes, int n_in,
                              void* d_out, int out_size, void* d_ws, size_t ws_size,
                              hipStream_t stream)
{
    const float* query = (const float*)d_in[0];
    const float* key   = (const float*)d_in[1];
    const float* value = (const float*)d_in[2];
    const float* w1    = (const float*)d_in[3];
    const float* b1    = (const float*)d_in[4];
    const float* w2    = (const float*)d_in[5];
    const float* b2    = (const float*)d_in[6];
    const float* wom   = (const float*)d_in[7];
    const float* bom   = (const float*)d_in[8];
    float* out = (float*)d_out;

    // workspace layout (floats): feat1 | feat2 | om | wT1 | wT2 | wTom
    // feat1 is dead after conv2, feat2 dead after conv_om -> reuse as kT/vT.
    float* ws    = (float*)d_ws;
    float* feat1 = ws;                                   // B*64*HW  (later kT)
    float* feat2 = feat1 + (size_t)B_ * 64 * HW_;        // B*64*HW  (later vT)
    float* ombuf = feat2 + (size_t)B_ * 64 * HW_;        // B*216*HW
    float* t1    = ombuf + (size_t)B_ * 216 * HW_;       // 1152*64
    float* t2    = t1 + 1152 * 64;                       // 576*64
    float* tom   = t2 + 576 * 64;                        // 576*216

    transpose_w<<<918, 256, 0, stream>>>(w1, w2, wom, t1, t2, tom);

    dim3 cgrid(W_ / 64, H_, B_);
    conv3_k<128, 64, true ><<<cgrid, 256, 0, stream>>>(query, key,  t1,  b1,  feat1);
    conv3_k< 64, 64, true ><<<cgrid, 256, 0, stream>>>(feat1, feat1, t2,  b2,  feat2);
    conv3_k< 64, 216, false><<<cgrid, 256, 0, stream>>>(feat2, feat2, tom, bom, ombuf);

    float* kT = feat1;   // overwrite dead feat buffers
    float* vT = feat2;
    dim3 tgrid(HW_ / 64, B_, 2);
    nchw_to_nhwc<<<tgrid, 256, 0, stream>>>(key, value, kT, vT);

    float* out_w = out;
    float* out_v = out + (size_t)B_ * HW_;
    sampler_k<<<(B_ * HW_) / 4, 256, 0, stream>>>(query, kT, vT, ombuf, out_w, out_v);
}

// Round 6
// 684.604 us; speedup vs baseline: 1.8339x; 1.1872x over previous
//
#include <hip/hip_runtime.h>
#include <math.h>

#define H_  192
#define W_  192
#define HW_ (192 * 192)
#define B_  2
#define C_  64

typedef __attribute__((ext_vector_type(8))) short short8;
typedef __attribute__((ext_vector_type(4))) short short4v;
typedef __attribute__((ext_vector_type(4))) float float4v;

// ---------------------------------------------------------------------------
// bf16 helpers (RNE)
// ---------------------------------------------------------------------------
__device__ __forceinline__ unsigned short f2bf(float f) {
    unsigned u = __float_as_uint(f);
    u += 0x7FFFu + ((u >> 16) & 1u);
    return (unsigned short)(u >> 16);
}
__device__ __forceinline__ float bf2f(unsigned short h) {
    return __uint_as_float((unsigned)h << 16);
}
// 3-limb split: x = h + m + l, each bf16; residual ~2^-27 * |x|
__device__ __forceinline__ void split3(float x, short& h, short& m, short& l) {
    unsigned short hh = f2bf(x);
    float r1 = x - bf2f(hh);
    unsigned short mm = f2bf(r1);
    float r2 = r1 - bf2f(mm);
    unsigned short ll = f2bf(r2);
    h = (short)hh; m = (short)mm; l = (short)ll;
}

// ---------------------------------------------------------------------------
__device__ __forceinline__ float wave_sum(float v) {
    #pragma unroll
    for (int off = 32; off > 0; off >>= 1)
        v += __shfl_xor(v, off, 64);
    return v;
}

// ---------------------------------------------------------------------------
// bilinear sample from NHWC fp32 plane ([HW][64] one batch), channel c
// ---------------------------------------------------------------------------
__device__ __forceinline__ float bilin_nhwc(const float* __restrict__ pl,
                                            float ys, float xs, int c) {
    float y0 = floorf(ys), x0 = floorf(xs);
    float fy = ys - y0, fx = xs - x0;
    int iy = (int)y0, ix = (int)x0;
    float acc = 0.f;
    #pragma unroll
    for (int dy = 0; dy < 2; ++dy) {
        #pragma unroll
        for (int dx = 0; dx < 2; ++dx) {
            int yy = iy + dy, xx = ix + dx;
            float wgt = (dy ? fy : 1.f - fy) * (dx ? fx : 1.f - fx);
            bool valid = (yy >= 0) && (yy < H_) && (xx >= 0) && (xx < W_);
            int yc = min(max(yy, 0), H_ - 1);
            int xc = min(max(xx, 0), W_ - 1);
            float g = pl[(size_t)(yc * W_ + xc) * 64 + c];
            acc += valid ? wgt * g : 0.f;
        }
    }
    return acc;
}

// ---------------------------------------------------------------------------
// weight pack: OIHW fp32 -> MFMA-fragment-ordered bf16 3-limb.
// frag elems: [frag][h:512][m:512][l:512] (stride 1536)
// frag = (mt*9 + kykx)*KS + s ; co = mt*16+(lane&15) ; ci = s*32+(lane>>4)*8+j
// pw1: 144 frags (MT=4,KS=4,CIN=128); pw2: 72 (MT=4,KS=2); pwom: 252 (MT=14,KS=2)
// ---------------------------------------------------------------------------
__global__ __launch_bounds__(256) void prep_w_k(
    const float* __restrict__ w1, const float* __restrict__ w2,
    const float* __restrict__ wom,
    short* __restrict__ pw1, short* __restrict__ pw2, short* __restrict__ pwom)
{
    int idx = blockIdx.x * 256 + threadIdx.x;
    int arr;
    if (idx < 144 * 512) { arr = 0; }
    else if (idx < (144 + 72) * 512) { arr = 1; idx -= 144 * 512; }
    else if (idx < (144 + 72 + 252) * 512) { arr = 2; idx -= (144 + 72) * 512; }
    else return;
    int frag = idx >> 9, within = idx & 511;
    int lane = within >> 3, j = within & 7;
    int KS   = (arr == 0) ? 4 : 2;
    int mt   = frag / (9 * KS);
    int rem  = frag % (9 * KS);
    int kk   = rem / KS;
    int s    = rem % KS;
    int co   = mt * 16 + (lane & 15);
    int c    = s * 32 + (lane >> 4) * 8 + j;
    float v = 0.f;
    if (arr == 0)      v = w1[(co * 128 + c) * 9 + kk];
    else if (arr == 1) v = w2[(co * 64 + c) * 9 + kk];
    else if (co < 216) v = wom[(co * 64 + c) * 9 + kk];
    short h, m, l;
    split3(v, h, m, l);
    short* dst = (arr == 0) ? pw1 : (arr == 1) ? pw2 : pwom;
    size_t base = (size_t)frag * 1536 + lane * 8 + j;
    dst[base]        = h;
    dst[base + 512]  = m;
    dst[base + 1024] = l;
}

// ---------------------------------------------------------------------------
// query/key NCHW fp32 -> packed NHWC bf16 3-limb:
// [p][h: q0-63,k64-127][m: ...][l: ...]  (pixel stride 384 shorts)
// ---------------------------------------------------------------------------
__global__ __launch_bounds__(256) void prep_qk_k(
    const float* __restrict__ query, const float* __restrict__ key,
    short* __restrict__ qk)
{
    __shared__ float sm[64][65];
    const int tid = threadIdx.x;
    const int p0  = blockIdx.x * 64;
    const int b   = blockIdx.y;
    const int z   = blockIdx.z;
    const float* src = z ? key : query;
    const int pp = tid & 63;
    const int r0 = tid >> 6;
    #pragma unroll
    for (int c = r0; c < 64; c += 4)
        sm[c][pp] = src[(size_t)(b * 64 + c) * HW_ + p0 + pp];
    __syncthreads();
    const int cc = tid & 63;
    #pragma unroll
    for (int pw = r0; pw < 64; pw += 4) {
        float v = sm[cc][pw];
        short h, m, l;
        split3(v, h, m, l);
        size_t base = ((size_t)b * HW_ + p0 + pw) * 384 + z * 64 + cc;
        qk[base]       = h;
        qk[base + 128] = m;
        qk[base + 256] = l;
    }
}

// ---------------------------------------------------------------------------
// NCHW -> NHWC fp32 transpose for key/value (sampler inputs)
// ---------------------------------------------------------------------------
__global__ __launch_bounds__(256) void nchw_to_nhwc(
    const float* __restrict__ key, const float* __restrict__ value,
    float* __restrict__ kT, float* __restrict__ vT)
{
    __shared__ float sm[64][65];
    const int tid = threadIdx.x;
    const int p0  = blockIdx.x * 64;
    const int b   = blockIdx.y;
    const float* src = blockIdx.z ? value : key;
    float*       dst = blockIdx.z ? vT    : kT;
    const int pp = tid & 63;
    const int r0 = tid >> 6;
    #pragma unroll
    for (int c = r0; c < 64; c += 4)
        sm[c][pp] = src[(size_t)(b * 64 + c) * HW_ + p0 + pp];
    __syncthreads();
    const int cc = tid & 63;
    #pragma unroll
    for (int pw = r0; pw < 64; pw += 4)
        dst[((size_t)b * HW_ + p0 + pw) * 64 + cc] = sm[cc][pw];
}

// ---------------------------------------------------------------------------
// implicit-GEMM 3x3 SAME conv via mfma_f32_16x16x32_bf16, 3-limb / 6-pass
// (hh + hm + mh + mm + hl + lh) -> product accuracy ~2^-25, fp32-grade.
// Block = 128 threads (2 waves). Wave w: M-tiles [w*MT/2,(w+1)*MT/2).
// N = 64 px (4 tiles of 16, one image row segment). No LDS.
// Input: packed NHWC 3-limb bf16 (stride 3*CIN). Weights: frag-packed.
// OUTMODE 0: out = packed feat 3-limb [p][h64][m64][l64] (lrelu)
// OUTMODE 1: out = om NHWC fp32 [p][216] (COUT=216 in M=224)
// ---------------------------------------------------------------------------
template<int CIN, int MT, bool LRELU, int OUTMODE>
__global__ __launch_bounds__(128) void conv_mfma(
    const short* __restrict__ in, const short* __restrict__ pw,
    const float* __restrict__ bias, void* __restrict__ outv)
{
    constexpr int KS  = CIN / 32;
    constexpr int MTW = MT / 2;
    const int lane = threadIdx.x & 63;
    const int w    = threadIdx.x >> 6;
    const int quad = lane >> 4;
    const int nn   = lane & 15;
    const int j0   = blockIdx.x * 64;
    const int i    = blockIdx.y;
    const int b    = blockIdx.z;
    const int mt0  = w * MTW;

    float4v acc[MTW][4];
    #pragma unroll
    for (int m = 0; m < MTW; ++m)
        #pragma unroll
        for (int t = 0; t < 4; ++t)
            #pragma unroll
            for (int r = 0; r < 4; ++r) acc[m][t][r] = 0.f;

    const short* inb = in + (size_t)b * HW_ * (3 * CIN);

    for (int kk = 0; kk < 9; ++kk) {
        const int ky  = kk / 3, kx = kk % 3;
        const int row = i + ky - 1;
        const bool rowok = (row >= 0) && (row < H_);
        for (int s = 0; s < KS; ++s) {
            short8 bh[4], bm[4], bl[4];
            #pragma unroll
            for (int t = 0; t < 4; ++t) {
                #pragma unroll
                for (int q = 0; q < 8; ++q) { bh[t][q] = 0; bm[t][q] = 0; bl[t][q] = 0; }
                int col = j0 + t * 16 + nn + kx - 1;
                if (rowok && col >= 0 && col < W_) {
                    const short* bp = inb + ((size_t)(row * W_ + col) * (3 * CIN)
                                             + s * 32 + quad * 8);
                    bh[t] = *(const short8*)bp;
                    bm[t] = *(const short8*)(bp + CIN);
                    bl[t] = *(const short8*)(bp + 2 * CIN);
                }
            }
            #pragma unroll
            for (int m = 0; m < MTW; ++m) {
                const short* ap = pw + ((size_t)(((mt0 + m) * 9 + kk) * KS + s)) * 1536
                                     + lane * 8;
                short8 ah = *(const short8*)ap;
                short8 am = *(const short8*)(ap + 512);
                short8 al = *(const short8*)(ap + 1024);
                #pragma unroll
                for (int t = 0; t < 4; ++t) {
                    acc[m][t] = __builtin_amdgcn_mfma_f32_16x16x32_bf16(ah, bh[t], acc[m][t], 0, 0, 0);
                    acc[m][t] = __builtin_amdgcn_mfma_f32_16x16x32_bf16(ah, bm[t], acc[m][t], 0, 0, 0);
                    acc[m][t] = __builtin_amdgcn_mfma_f32_16x16x32_bf16(am, bh[t], acc[m][t], 0, 0, 0);
                    acc[m][t] = __builtin_amdgcn_mfma_f32_16x16x32_bf16(am, bm[t], acc[m][t], 0, 0, 0);
                    acc[m][t] = __builtin_amdgcn_mfma_f32_16x16x32_bf16(ah, bl[t], acc[m][t], 0, 0, 0);
                    acc[m][t] = __builtin_amdgcn_mfma_f32_16x16x32_bf16(al, bh[t], acc[m][t], 0, 0, 0);
                }
            }
        }
    }

    // epilogue: C/D layout col(=px)=lane&15, row(=co)=quad*4+reg (verified m89)
    #pragma unroll
    for (int m = 0; m < MTW; ++m) {
        const int co0 = (mt0 + m) * 16 + quad * 4;
        #pragma unroll
        for (int t = 0; t < 4; ++t) {
            const int p = i * W_ + j0 + t * 16 + nn;
            if (OUTMODE == 0) {
                short* feat = (short*)outv;
                short4v hv, mv, lv;
                #pragma unroll
                for (int r = 0; r < 4; ++r) {
                    float x = acc[m][t][r] + bias[co0 + r];
                    if (LRELU) x = (x >= 0.f) ? x : 0.1f * x;
                    short h, mm, l;
                    split3(x, h, mm, l);
                    hv[r] = h; mv[r] = mm; lv[r] = l;
                }
                short* dp = feat + ((size_t)b * HW_ + p) * 192 + co0;
                *(short4v*)dp         = hv;
                *(short4v*)(dp + 64)  = mv;
                *(short4v*)(dp + 128) = lv;
            } else {
                if (co0 < 216) {
                    float* om = (float*)outv;
                    float4v v;
                    #pragma unroll
                    for (int r = 0; r < 4; ++r)
                        v[r] = acc[m][t][r] + bias[co0 + r];
                    *(float4v*)(om + ((size_t)b * HW_ + p) * 216 + co0) = v;
                }
            }
        }
    }
}

// ---------------------------------------------------------------------------
// fused deformable sampling + top-2 attention (om NHWC [p][216])
// ---------------------------------------------------------------------------
__global__ __launch_bounds__(256) void sampler_k(
    const float* __restrict__ query, const float* __restrict__ kT,
    const float* __restrict__ vT, const float* __restrict__ om,
    float* __restrict__ out_w, float* __restrict__ out_v)
{
    const int lane = threadIdx.x & 63;
    const int wid  = threadIdx.x >> 6;
    const int P    = blockIdx.x * 4 + wid;
    const int b    = (P >= HW_) ? 1 : 0;
    const int p    = P - b * HW_;
    const int i    = p / W_;
    const int j    = p - i * W_;
    const int c    = lane;
    const int g    = lane >> 3;

    const float qc   = query[(size_t)(b * C_ + c) * HW_ + p];
    const float* omb = om + ((size_t)b * HW_ + p) * 216;

    float offy[9], offx[9], mk[9];
    #pragma unroll
    for (int n = 0; n < 9; ++n) {
        offy[n] = omb[g * 9 + n];
        offx[n] = omb[72 + g * 9 + n];
        float mv = omb[144 + g * 9 + n];
        mk[n] = 1.f / (1.f + expf(-mv));
    }

    const float* kpl = kT + (size_t)b * HW_ * 64;
    float kv[9], rel[9];
    #pragma unroll
    for (int n = 0; n < 9; ++n) {
        float ys = (float)i + (float)(n / 3 - 1) + offy[n];
        float xs = (float)j + (float)(n % 3 - 1) + offx[n];
        kv[n]  = bilin_nhwc(kpl, ys, xs, c) * mk[n];
        rel[n] = wave_sum(kv[n] * qc);
    }

    int n0 = 0; float v0 = rel[0];
    #pragma unroll
    for (int n = 1; n < 9; ++n) { if (rel[n] > v0) { v0 = rel[n]; n0 = n; } }
    int n1 = -1; float v1 = -1e30f;
    #pragma unroll
    for (int n = 0; n < 9; ++n) { if (n != n0 && rel[n] > v1) { v1 = rel[n]; n1 = n; } }

    float e1  = expf(v1 - v0);
    float inv = 1.f / (1.f + e1);
    float c0 = inv, c1 = e1 * inv;

    float kv0 = 0, kv1 = 0, oy0 = 0, ox0 = 0, m0 = 0, oy1 = 0, ox1 = 0, m1 = 0;
    #pragma unroll
    for (int n = 0; n < 9; ++n) {
        if (n == n0) { kv0 = kv[n]; oy0 = offy[n]; ox0 = offx[n]; m0 = mk[n]; }
        if (n == n1) { kv1 = kv[n]; oy1 = offy[n]; ox1 = offx[n]; m1 = mk[n]; }
    }

    float kupd = c0 * kv0 + c1 * kv1;
    float wsum = wave_sum(qc * kupd);
    if (lane == 0) out_w[(size_t)b * HW_ + p] = wsum;

    const float* vpl = vT + (size_t)b * HW_ * 64;
    float ys0 = (float)i + (float)(n0 / 3 - 1) + oy0;
    float xs0 = (float)j + (float)(n0 % 3 - 1) + ox0;
    float ys1 = (float)i + (float)(n1 / 3 - 1) + oy1;
    float xs1 = (float)j + (float)(n1 % 3 - 1) + ox1;
    float vv0 = bilin_nhwc(vpl, ys0, xs0, c) * m0;
    float vv1 = bilin_nhwc(vpl, ys1, xs1, c) * m1;
    out_v[(size_t)(b * C_ + c) * HW_ + p] = c0 * vv0 + c1 * vv1;
}

// ---------------------------------------------------------------------------
extern "C" void kernel_launch(void* const* d_in, const int* in_sizes, int n_in,
                              void* d_out, int out_size, void* d_ws, size_t ws_size,
                              hipStream_t stream)
{
    const float* query = (const float*)d_in[0];
    const float* key   = (const float*)d_in[1];
    const float* value = (const float*)d_in[2];
    const float* w1    = (const float*)d_in[3];
    const float* b1    = (const float*)d_in[4];
    const float* w2    = (const float*)d_in[5];
    const float* b2    = (const float*)d_in[6];
    const float* wom   = (const float*)d_in[7];
    const float* bom   = (const float*)d_in[8];
    float* out = (float*)d_out;

    // Liveness-packed workspace, TOTAL = 101,449,728 B (< 102,666,240 proven
    // safe in round 3). Kernel order: prep_w(s1) prep_qk(s2) conv1(s3)
    // conv2(s4) conv_om(s5) nchw(s6) sampler(s7).
    //   f1   @0          +28,311,552   live s3-s4
    //   om   @0          +63,700,992   live s5-s7   (over dead f1)
    //   qk   @28,311,552 +56,623,104   live s2-s3   (under later om/f2: both
    //                                   written s4+; disjoint from f1 at s3)
    //   f2   @63,700,992 +28,311,552   live s4-s5   (over dead qk tail)
    //   kT   @63,700,992 +18,874,368   live s6-s7   (over dead f2)
    //   vT   @82,575,360 +18,874,368   live s6-s7   (over dead f2/pw)
    //   pwom @92,012,544 +774,144      live s1-s5
    //   pw1  @92,786,688 +442,368      live s1-s3
    //   pw2  @93,229,056 +221,184      live s1-s4
    char* ws = (char*)d_ws;
    short* f1  = (short*)(ws);
    float* om  = (float*)(ws);
    short* qk  = (short*)(ws + 28311552);
    short* f2  = (short*)(ws + 63700992);
    float* kT  = (float*)(ws + 63700992);
    float* vT  = (float*)(ws + 82575360);
    short* pwom= (short*)(ws + 92012544);
    short* pw1 = (short*)(ws + 92786688);
    short* pw2 = (short*)(ws + 93229056);

    prep_w_k<<<936, 256, 0, stream>>>(w1, w2, wom, pw1, pw2, pwom);
    prep_qk_k<<<dim3(576, B_, 2), 256, 0, stream>>>(query, key, qk);

    dim3 cgrid(3, H_, B_);
    conv_mfma<128, 4,  true,  0><<<cgrid, 128, 0, stream>>>(qk, pw1, b1, (void*)f1);
    conv_mfma<64,  4,  true,  0><<<cgrid, 128, 0, stream>>>(f1, pw2, b2, (void*)f2);
    conv_mfma<64,  14, false, 1><<<cgrid, 128, 0, stream>>>(f2, pwom, bom, (void*)om);

    nchw_to_nhwc<<<dim3(576, B_, 2), 256, 0, stream>>>(key, value, kT, vT);

    float* out_w = out;
    float* out_v = out + (size_t)B_ * HW_;
    sampler_k<<<(B_ * HW_) / 4, 256, 0, stream>>>(query, kT, vT, om, out_w, out_v);
}

// Round 7
// 666.570 us; speedup vs baseline: 1.8835x; 1.0271x over previous
//
#include <hip/hip_runtime.h>
#include <math.h>

#define H_  192
#define W_  192
#define HW_ (192 * 192)
#define B_  2
#define C_  64

typedef __attribute__((ext_vector_type(8))) short short8;
typedef __attribute__((ext_vector_type(4))) short short4v;
typedef __attribute__((ext_vector_type(4))) float float4v;

// ---------------------------------------------------------------------------
// bf16 helpers (RNE)
// ---------------------------------------------------------------------------
__device__ __forceinline__ unsigned short f2bf(float f) {
    unsigned u = __float_as_uint(f);
    u += 0x7FFFu + ((u >> 16) & 1u);
    return (unsigned short)(u >> 16);
}
__device__ __forceinline__ float bf2f(unsigned short h) {
    return __uint_as_float((unsigned)h << 16);
}
// 3-limb split: x = h + m + l, each bf16; residual ~2^-27 * |x|
__device__ __forceinline__ void split3(float x, short& h, short& m, short& l) {
    unsigned short hh = f2bf(x);
    float r1 = x - bf2f(hh);
    unsigned short mm = f2bf(r1);
    float r2 = r1 - bf2f(mm);
    unsigned short ll = f2bf(r2);
    h = (short)hh; m = (short)mm; l = (short)ll;
}

// ---------------------------------------------------------------------------
__device__ __forceinline__ float wave_sum(float v) {
    #pragma unroll
    for (int off = 32; off > 0; off >>= 1)
        v += __shfl_xor(v, off, 64);
    return v;
}

// ---------------------------------------------------------------------------
// bilinear sample from NHWC fp32 plane ([HW][64] one batch), channel c
// ---------------------------------------------------------------------------
__device__ __forceinline__ float bilin_nhwc(const float* __restrict__ pl,
                                            float ys, float xs, int c) {
    float y0 = floorf(ys), x0 = floorf(xs);
    float fy = ys - y0, fx = xs - x0;
    int iy = (int)y0, ix = (int)x0;
    float acc = 0.f;
    #pragma unroll
    for (int dy = 0; dy < 2; ++dy) {
        #pragma unroll
        for (int dx = 0; dx < 2; ++dx) {
            int yy = iy + dy, xx = ix + dx;
            float wgt = (dy ? fy : 1.f - fy) * (dx ? fx : 1.f - fx);
            bool valid = (yy >= 0) && (yy < H_) && (xx >= 0) && (xx < W_);
            int yc = min(max(yy, 0), H_ - 1);
            int xc = min(max(xx, 0), W_ - 1);
            float g = pl[(size_t)(yc * W_ + xc) * 64 + c];
            acc += valid ? wgt * g : 0.f;
        }
    }
    return acc;
}

// ---------------------------------------------------------------------------
// weight pack: OIHW fp32 -> MFMA-fragment-ordered bf16 3-limb.
// frag elems: [frag][h:512][m:512][l:512] (stride 1536)
// frag = (mt*9 + kykx)*KS + s ; co = mt*16+(lane&15) ; ci = s*32+(lane>>4)*8+j
// pw1: 144 frags (MT=4,KS=4,CIN=128); pw2: 72 (MT=4,KS=2); pwom: 252 (MT=14,KS=2)
// ---------------------------------------------------------------------------
__global__ __launch_bounds__(256) void prep_w_k(
    const float* __restrict__ w1, const float* __restrict__ w2,
    const float* __restrict__ wom,
    short* __restrict__ pw1, short* __restrict__ pw2, short* __restrict__ pwom)
{
    int idx = blockIdx.x * 256 + threadIdx.x;
    int arr;
    if (idx < 144 * 512) { arr = 0; }
    else if (idx < (144 + 72) * 512) { arr = 1; idx -= 144 * 512; }
    else if (idx < (144 + 72 + 252) * 512) { arr = 2; idx -= (144 + 72) * 512; }
    else return;
    int frag = idx >> 9, within = idx & 511;
    int lane = within >> 3, j = within & 7;
    int KS   = (arr == 0) ? 4 : 2;
    int mt   = frag / (9 * KS);
    int rem  = frag % (9 * KS);
    int kk   = rem / KS;
    int s    = rem % KS;
    int co   = mt * 16 + (lane & 15);
    int c    = s * 32 + (lane >> 4) * 8 + j;
    float v = 0.f;
    if (arr == 0)      v = w1[(co * 128 + c) * 9 + kk];
    else if (arr == 1) v = w2[(co * 64 + c) * 9 + kk];
    else if (co < 216) v = wom[(co * 64 + c) * 9 + kk];
    short h, m, l;
    split3(v, h, m, l);
    short* dst = (arr == 0) ? pw1 : (arr == 1) ? pw2 : pwom;
    size_t base = (size_t)frag * 1536 + lane * 8 + j;
    dst[base]        = h;
    dst[base + 512]  = m;
    dst[base + 1024] = l;
}

// ---------------------------------------------------------------------------
// NCHW -> NHWC fp32 transpose for key/value (sampler inputs)
// ---------------------------------------------------------------------------
__global__ __launch_bounds__(256) void nchw_to_nhwc(
    const float* __restrict__ key, const float* __restrict__ value,
    float* __restrict__ kT, float* __restrict__ vT)
{
    __shared__ float sm[64][65];
    const int tid = threadIdx.x;
    const int p0  = blockIdx.x * 64;
    const int b   = blockIdx.y;
    const float* src = blockIdx.z ? value : key;
    float*       dst = blockIdx.z ? vT    : kT;
    const int pp = tid & 63;
    const int r0 = tid >> 6;
    #pragma unroll
    for (int c = r0; c < 64; c += 4)
        sm[c][pp] = src[(size_t)(b * 64 + c) * HW_ + p0 + pp];
    __syncthreads();
    const int cc = tid & 63;
    #pragma unroll
    for (int pw = r0; pw < 64; pw += 4)
        dst[((size_t)b * HW_ + p0 + pw) * 64 + cc] = sm[cc][pw];
}

// ---------------------------------------------------------------------------
// implicit-GEMM 3x3 SAME conv via mfma_f32_16x16x32_bf16, 3-limb / 6-pass.
// Block = 128 threads (2 waves, M-split). N = 64 px of one image row.
// LDS-staged B: per (ky, s) chunk, 66 px x 32 ci x 3 limbs staged once
// (stride 104 shorts -> 16B-aligned ds_read_b128, ~2-way bank alias = free),
// read by both waves -> kills the 18x global re-fetch of round 6.
// FROMF32=true (conv1): stage directly from fp32 NCHW query/key with on-the-
// fly split3 (no packed qk intermediate). Else stage from packed 3-limb feat.
// OUTMODE 0: packed feat 3-limb [p][h64][m64][l64] (+lrelu)
// OUTMODE 1: om NHWC fp32 [p][216] (COUT=216 in M=224)
// ---------------------------------------------------------------------------
template<int CIN, int MT, bool LRELU, int OUTMODE, bool FROMF32>
__global__ __launch_bounds__(128) void conv_mfma(
    const void* __restrict__ in0v, const void* __restrict__ in1v,
    const short* __restrict__ pw, const float* __restrict__ bias,
    void* __restrict__ outv)
{
    constexpr int KS   = CIN / 32;
    constexpr int MTW  = MT / 2;
    constexpr int LSTR = 104;                  // shorts per px: 3*32 + 8 pad
    __shared__ __align__(16) short smem[66 * LSTR];

    const int tid  = threadIdx.x;
    const int lane = tid & 63;
    const int w    = tid >> 6;
    const int quad = lane >> 4;
    const int nn   = lane & 15;
    const int j0   = blockIdx.x * 64;
    const int i    = blockIdx.y;
    const int b    = blockIdx.z;
    const int mt0  = w * MTW;

    float4v acc[MTW][4];
    #pragma unroll
    for (int m = 0; m < MTW; ++m)
        #pragma unroll
        for (int t = 0; t < 4; ++t)
            #pragma unroll
            for (int r = 0; r < 4; ++r) acc[m][t][r] = 0.f;

    for (int ky = 0; ky < 3; ++ky) {
        const int row = i + ky - 1;
        const bool rowok = (row >= 0) && (row < H_);
        for (int s = 0; s < KS; ++s) {
            __syncthreads();
            if (FROMF32) {
                // conv1: src plane q (s<2) / k (s>=2), 32 fp32 ch -> 3 limbs
                const float* src = (s < KS / 2) ? (const float*)in0v
                                                : (const float*)in1v;
                const int cbase = (s & (KS / 2 - 1)) * 32;
                for (int idx = tid; idx < 32 * 66; idx += 128) {
                    int ci = idx / 66, px = idx - ci * 66;
                    int col = j0 - 1 + px;
                    float v = 0.f;
                    if (rowok && col >= 0 && col < W_)
                        v = src[(size_t)(b * 64 + cbase + ci) * HW_ + row * W_ + col];
                    short h, m, l;
                    split3(v, h, m, l);
                    smem[px * LSTR + ci]      = h;
                    smem[px * LSTR + 32 + ci] = m;
                    smem[px * LSTR + 64 + ci] = l;
                }
            } else {
                // packed 3-limb feat [p][limb*CIN + ci], copy 8B at a time
                const short* src = (const short*)in0v
                                 + (size_t)b * HW_ * (3 * CIN);
                for (int idx = tid; idx < 66 * 24; idx += 128) {
                    int px = idx / 24, r = idx - px * 24;
                    int limb = r >> 3, dq = r & 7;
                    int col = j0 - 1 + px;
                    unsigned long long v = 0;
                    if (rowok && col >= 0 && col < W_)
                        v = *(const unsigned long long*)(src
                              + (size_t)(row * W_ + col) * (3 * CIN)
                              + limb * CIN + s * 32 + dq * 4);
                    *(unsigned long long*)(&smem[px * LSTR + limb * 32 + dq * 4]) = v;
                }
            }
            __syncthreads();

            #pragma unroll
            for (int kx = 0; kx < 3; ++kx) {
                const int kk = ky * 3 + kx;
                short8 bh[4], bm[4], bl[4];
                #pragma unroll
                for (int t = 0; t < 4; ++t) {
                    const short* bp = &smem[(t * 16 + nn + kx) * LSTR + quad * 8];
                    bh[t] = *(const short8*)bp;
                    bm[t] = *(const short8*)(bp + 32);
                    bl[t] = *(const short8*)(bp + 64);
                }
                #pragma unroll
                for (int m = 0; m < MTW; ++m) {
                    const short* ap = pw
                        + ((size_t)(((mt0 + m) * 9 + kk) * KS + s)) * 1536
                        + lane * 8;
                    short8 ah = *(const short8*)ap;
                    short8 am = *(const short8*)(ap + 512);
                    short8 al = *(const short8*)(ap + 1024);
                    #pragma unroll
                    for (int t = 0; t < 4; ++t) {
                        acc[m][t] = __builtin_amdgcn_mfma_f32_16x16x32_bf16(ah, bh[t], acc[m][t], 0, 0, 0);
                        acc[m][t] = __builtin_amdgcn_mfma_f32_16x16x32_bf16(ah, bm[t], acc[m][t], 0, 0, 0);
                        acc[m][t] = __builtin_amdgcn_mfma_f32_16x16x32_bf16(am, bh[t], acc[m][t], 0, 0, 0);
                        acc[m][t] = __builtin_amdgcn_mfma_f32_16x16x32_bf16(am, bm[t], acc[m][t], 0, 0, 0);
                        acc[m][t] = __builtin_amdgcn_mfma_f32_16x16x32_bf16(ah, bl[t], acc[m][t], 0, 0, 0);
                        acc[m][t] = __builtin_amdgcn_mfma_f32_16x16x32_bf16(al, bh[t], acc[m][t], 0, 0, 0);
                    }
                }
            }
        }
    }

    // epilogue: C/D layout col(=px)=lane&15, row(=co)=quad*4+reg (verified m89)
    #pragma unroll
    for (int m = 0; m < MTW; ++m) {
        const int co0 = (mt0 + m) * 16 + quad * 4;
        #pragma unroll
        for (int t = 0; t < 4; ++t) {
            const int p = i * W_ + j0 + t * 16 + nn;
            if (OUTMODE == 0) {
                short* feat = (short*)outv;
                short4v hv, mv, lv;
                #pragma unroll
                for (int r = 0; r < 4; ++r) {
                    float x = acc[m][t][r] + bias[co0 + r];
                    if (LRELU) x = (x >= 0.f) ? x : 0.1f * x;
                    short h, mm, l;
                    split3(x, h, mm, l);
                    hv[r] = h; mv[r] = mm; lv[r] = l;
                }
                short* dp = feat + ((size_t)b * HW_ + p) * 192 + co0;
                *(short4v*)dp         = hv;
                *(short4v*)(dp + 64)  = mv;
                *(short4v*)(dp + 128) = lv;
            } else {
                if (co0 < 216) {
                    float* om = (float*)outv;
                    float4v v;
                    #pragma unroll
                    for (int r = 0; r < 4; ++r)
                        v[r] = acc[m][t][r] + bias[co0 + r];
                    *(float4v*)(om + ((size_t)b * HW_ + p) * 216 + co0) = v;
                }
            }
        }
    }
}

// ---------------------------------------------------------------------------
// fused deformable sampling + top-2 attention (om NHWC [p][216])
// ---------------------------------------------------------------------------
__global__ __launch_bounds__(256) void sampler_k(
    const float* __restrict__ query, const float* __restrict__ kT,
    const float* __restrict__ vT, const float* __restrict__ om,
    float* __restrict__ out_w, float* __restrict__ out_v)
{
    const int lane = threadIdx.x & 63;
    const int wid  = threadIdx.x >> 6;
    const int P    = blockIdx.x * 4 + wid;
    const int b    = (P >= HW_) ? 1 : 0;
    const int p    = P - b * HW_;
    const int i    = p / W_;
    const int j    = p - i * W_;
    const int c    = lane;
    const int g    = lane >> 3;

    const float qc   = query[(size_t)(b * C_ + c) * HW_ + p];
    const float* omb = om + ((size_t)b * HW_ + p) * 216;

    float offy[9], offx[9], mk[9];
    #pragma unroll
    for (int n = 0; n < 9; ++n) {
        offy[n] = omb[g * 9 + n];
        offx[n] = omb[72 + g * 9 + n];
        float mv = omb[144 + g * 9 + n];
        mk[n] = 1.f / (1.f + expf(-mv));
    }

    const float* kpl = kT + (size_t)b * HW_ * 64;
    float kv[9], rel[9];
    #pragma unroll
    for (int n = 0; n < 9; ++n) {
        float ys = (float)i + (float)(n / 3 - 1) + offy[n];
        float xs = (float)j + (float)(n % 3 - 1) + offx[n];
        kv[n]  = bilin_nhwc(kpl, ys, xs, c) * mk[n];
        rel[n] = wave_sum(kv[n] * qc);
    }

    int n0 = 0; float v0 = rel[0];
    #pragma unroll
    for (int n = 1; n < 9; ++n) { if (rel[n] > v0) { v0 = rel[n]; n0 = n; } }
    int n1 = -1; float v1 = -1e30f;
    #pragma unroll
    for (int n = 0; n < 9; ++n) { if (n != n0 && rel[n] > v1) { v1 = rel[n]; n1 = n; } }

    float e1  = expf(v1 - v0);
    float inv = 1.f / (1.f + e1);
    float c0 = inv, c1 = e1 * inv;

    float kv0 = 0, kv1 = 0, oy0 = 0, ox0 = 0, m0 = 0, oy1 = 0, ox1 = 0, m1 = 0;
    #pragma unroll
    for (int n = 0; n < 9; ++n) {
        if (n == n0) { kv0 = kv[n]; oy0 = offy[n]; ox0 = offx[n]; m0 = mk[n]; }
        if (n == n1) { kv1 = kv[n]; oy1 = offy[n]; ox1 = offx[n]; m1 = mk[n]; }
    }

    float kupd = c0 * kv0 + c1 * kv1;
    float wsum = wave_sum(qc * kupd);
    if (lane == 0) out_w[(size_t)b * HW_ + p] = wsum;

    const float* vpl = vT + (size_t)b * HW_ * 64;
    float ys0 = (float)i + (float)(n0 / 3 - 1) + oy0;
    float xs0 = (float)j + (float)(n0 % 3 - 1) + ox0;
    float ys1 = (float)i + (float)(n1 / 3 - 1) + oy1;
    float xs1 = (float)j + (float)(n1 % 3 - 1) + ox1;
    float vv0 = bilin_nhwc(vpl, ys0, xs0, c) * m0;
    float vv1 = bilin_nhwc(vpl, ys1, xs1, c) * m1;
    out_v[(size_t)(b * C_ + c) * HW_ + p] = c0 * vv0 + c1 * vv1;
}

// ---------------------------------------------------------------------------
extern "C" void kernel_launch(void* const* d_in, const int* in_sizes, int n_in,
                              void* d_out, int out_size, void* d_ws, size_t ws_size,
                              hipStream_t stream)
{
    const float* query = (const float*)d_in[0];
    const float* key   = (const float*)d_in[1];
    const float* value = (const float*)d_in[2];
    const float* w1    = (const float*)d_in[3];
    const float* b1    = (const float*)d_in[4];
    const float* w2    = (const float*)d_in[5];
    const float* b2    = (const float*)d_in[6];
    const float* wom   = (const float*)d_in[7];
    const float* bom   = (const float*)d_in[8];
    float* out = (float*)d_out;

    // Liveness-packed workspace, TOTAL = 101,449,728 B (= round-6 proven size).
    // Stages: prep_w(s1) conv1(s3) conv2(s4) conv_om(s5) nchw(s6) sampler(s7).
    //   f1   @0          +28,311,552   live s3-s4
    //   om   @0          +63,700,992   live s5-s7   (over dead f1)
    //   f2   @63,700,992 +28,311,552   live s4-s5
    //   kT   @63,700,992 +18,874,368   live s6-s7   (over dead f2)
    //   vT   @82,575,360 +18,874,368   live s6-s7   (over dead f2/pw tail)
    //   pwom @92,012,544 +774,144      live s1-s5   (under vT: vT written s6)
    //   pw1  @92,786,688 +442,368      live s1-s3
    //   pw2  @93,229,056 +221,184      live s1-s4
    char* ws = (char*)d_ws;
    short* f1  = (short*)(ws);
    float* om  = (float*)(ws);
    short* f2  = (short*)(ws + 63700992);
    float* kT  = (float*)(ws + 63700992);
    float* vT  = (float*)(ws + 82575360);
    short* pwom= (short*)(ws + 92012544);
    short* pw1 = (short*)(ws + 92786688);
    short* pw2 = (short*)(ws + 93229056);

    prep_w_k<<<936, 256, 0, stream>>>(w1, w2, wom, pw1, pw2, pwom);

    dim3 cgrid(3, H_, B_);
    conv_mfma<128, 4,  true,  0, true ><<<cgrid, 128, 0, stream>>>(query, key, pw1, b1, (void*)f1);
    conv_mfma<64,  4,  true,  0, false><<<cgrid, 128, 0, stream>>>(f1, nullptr, pw2, b2, (void*)f2);
    conv_mfma<64,  14, false, 1, false><<<cgrid, 128, 0, stream>>>(f2, nullptr, pwom, bom, (void*)om);

    nchw_to_nhwc<<<dim3(576, B_, 2), 256, 0, stream>>>(key, value, kT, vT);

    float* out_w = out;
    float* out_v = out + (size_t)B_ * HW_;
    sampler_k<<<(B_ * HW_) / 4, 256, 0, stream>>>(query, kT, vT, om, out_w, out_v);
}

// Round 8
// 510.289 us; speedup vs baseline: 2.4604x; 1.3063x over previous
//
#include <hip/hip_runtime.h>
#include <math.h>

#define H_  192
#define W_  192
#define HW_ (192 * 192)
#define B_  2
#define C_  64

typedef __attribute__((ext_vector_type(8))) short short8;
typedef __attribute__((ext_vector_type(4))) short short4v;
typedef __attribute__((ext_vector_type(4))) float float4v;

// ---------------------------------------------------------------------------
// bf16 helpers (RNE)
// ---------------------------------------------------------------------------
__device__ __forceinline__ unsigned short f2bf(float f) {
    unsigned u = __float_as_uint(f);
    u += 0x7FFFu + ((u >> 16) & 1u);
    return (unsigned short)(u >> 16);
}
__device__ __forceinline__ float bf2f(unsigned short h) {
    return __uint_as_float((unsigned)h << 16);
}
// 3-limb split: x = h + m + l, each bf16; residual ~2^-27 * |x|
__device__ __forceinline__ void split3(float x, short& h, short& m, short& l) {
    unsigned short hh = f2bf(x);
    float r1 = x - bf2f(hh);
    unsigned short mm = f2bf(r1);
    float r2 = r1 - bf2f(mm);
    unsigned short ll = f2bf(r2);
    h = (short)hh; m = (short)mm; l = (short)ll;
}

// ---------------------------------------------------------------------------
__device__ __forceinline__ float wave_sum(float v) {
    #pragma unroll
    for (int off = 32; off > 0; off >>= 1)
        v += __shfl_xor(v, off, 64);
    return v;
}

// ---------------------------------------------------------------------------
// bilinear sample from NHWC fp32 plane ([HW][64] one batch), channel c
// ---------------------------------------------------------------------------
__device__ __forceinline__ float bilin_nhwc(const float* __restrict__ pl,
                                            float ys, float xs, int c) {
    float y0 = floorf(ys), x0 = floorf(xs);
    float fy = ys - y0, fx = xs - x0;
    int iy = (int)y0, ix = (int)x0;
    float acc = 0.f;
    #pragma unroll
    for (int dy = 0; dy < 2; ++dy) {
        #pragma unroll
        for (int dx = 0; dx < 2; ++dx) {
            int yy = iy + dy, xx = ix + dx;
            float wgt = (dy ? fy : 1.f - fy) * (dx ? fx : 1.f - fx);
            bool valid = (yy >= 0) && (yy < H_) && (xx >= 0) && (xx < W_);
            int yc = min(max(yy, 0), H_ - 1);
            int xc = min(max(xx, 0), W_ - 1);
            float g = pl[(size_t)(yc * W_ + xc) * 64 + c];
            acc += valid ? wgt * g : 0.f;
        }
    }
    return acc;
}

// ---------------------------------------------------------------------------
// weight pack: OIHW fp32 -> MFMA-fragment-ordered bf16 3-limb.
// frag elems: [frag][h:512][m:512][l:512] (stride 1536)
// frag = (mt*9 + kykx)*KS + s ; co = mt*16+(lane&15) ; ci = s*32+(lane>>4)*8+j
// pw1: 144 frags (MT=4,KS=4,CIN=128); pw2: 72 (MT=4,KS=2); pwom: 252 (MT=14,KS=2)
// ---------------------------------------------------------------------------
__global__ __launch_bounds__(256) void prep_w_k(
    const float* __restrict__ w1, const float* __restrict__ w2,
    const float* __restrict__ wom,
    short* __restrict__ pw1, short* __restrict__ pw2, short* __restrict__ pwom)
{
    int idx = blockIdx.x * 256 + threadIdx.x;
    int arr;
    if (idx < 144 * 512) { arr = 0; }
    else if (idx < (144 + 72) * 512) { arr = 1; idx -= 144 * 512; }
    else if (idx < (144 + 72 + 252) * 512) { arr = 2; idx -= (144 + 72) * 512; }
    else return;
    int frag = idx >> 9, within = idx & 511;
    int lane = within >> 3, j = within & 7;
    int KS   = (arr == 0) ? 4 : 2;
    int mt   = frag / (9 * KS);
    int rem  = frag % (9 * KS);
    int kk   = rem / KS;
    int s    = rem % KS;
    int co   = mt * 16 + (lane & 15);
    int c    = s * 32 + (lane >> 4) * 8 + j;
    float v = 0.f;
    if (arr == 0)      v = w1[(co * 128 + c) * 9 + kk];
    else if (arr == 1) v = w2[(co * 64 + c) * 9 + kk];
    else if (co < 216) v = wom[(co * 64 + c) * 9 + kk];
    short h, m, l;
    split3(v, h, m, l);
    short* dst = (arr == 0) ? pw1 : (arr == 1) ? pw2 : pwom;
    size_t base = (size_t)frag * 1536 + lane * 8 + j;
    dst[base]        = h;
    dst[base + 512]  = m;
    dst[base + 1024] = l;
}

// ---------------------------------------------------------------------------
// NCHW -> NHWC fp32 transpose for key/value (sampler inputs)
// ---------------------------------------------------------------------------
__global__ __launch_bounds__(256) void nchw_to_nhwc(
    const float* __restrict__ key, const float* __restrict__ value,
    float* __restrict__ kT, float* __restrict__ vT)
{
    __shared__ float sm[64][65];
    const int tid = threadIdx.x;
    const int p0  = blockIdx.x * 64;
    const int b   = blockIdx.y;
    const float* src = blockIdx.z ? value : key;
    float*       dst = blockIdx.z ? vT    : kT;
    const int pp = tid & 63;
    const int r0 = tid >> 6;
    #pragma unroll
    for (int c = r0; c < 64; c += 4)
        sm[c][pp] = src[(size_t)(b * 64 + c) * HW_ + p0 + pp];
    __syncthreads();
    const int cc = tid & 63;
    #pragma unroll
    for (int pw = r0; pw < 64; pw += 4)
        dst[((size_t)b * HW_ + p0 + pw) * 64 + cc] = sm[cc][pw];
}

// ---------------------------------------------------------------------------
// implicit-GEMM 3x3 SAME conv via mfma_f32_16x16x32_bf16, 3-limb / 6-pass.
// Block = 256 threads (4 waves), wave (wh, wn) = (M-half, N-half) quadrant:
//   wave acc = (MT/2) x 2 x 4 VGPRs (conv_om: 56 vs round-7's 112).
// N = 64 px of one image row; LDS stages 66 px x 32 ci x 3 limbs per (ky,s),
// written once by 256 threads, read by all 4 waves.
// 1D grid 1152, XCD-affine swizzle: xcd=flat&7 owns a 48-row band of one
// batch -> ky-halo rows + pw weights stay in that XCD's L2.
// FROMF32 (conv1): stages fp32 NCHW query/key with on-the-fly split3.
// OUTMODE 0: packed feat 3-limb [p][h64][m64][l64] (+lrelu)
// OUTMODE 1: om NHWC fp32 [p][216] (COUT=216 in M=224)
// ---------------------------------------------------------------------------
template<int CIN, int MT, bool LRELU, int OUTMODE, bool FROMF32>
__global__ __launch_bounds__(256) void conv_mfma(
    const void* __restrict__ in0v, const void* __restrict__ in1v,
    const short* __restrict__ pw, const float* __restrict__ bias,
    void* __restrict__ outv)
{
    constexpr int KS   = CIN / 32;
    constexpr int MTW  = MT / 2;               // M-tiles per wave
    constexpr int LSTR = 104;                  // shorts per px: 3*32 + 8 pad
    __shared__ __align__(16) short smem[66 * LSTR];

    const int tid  = threadIdx.x;
    const int lane = tid & 63;
    const int w    = tid >> 6;                 // 0..3
    const int wh   = w & 1;                    // M-half
    const int wn   = w >> 1;                   // N-half
    const int quad = lane >> 4;
    const int nn   = lane & 15;

    // XCD-affine swizzle (1152 blocks = 8 xcd * 144)
    const int flat = blockIdx.x;
    const int xcd  = flat & 7;
    const int cc_  = flat >> 3;                // 0..143
    const int b    = xcd >> 2;                 // batch
    const int r4   = xcd & 3;
    const int i    = r4 * 48 + cc_ / 3;        // row
    const int j0   = (cc_ % 3) * 64;
    const int mt0  = wh * MTW;

    float4v acc[MTW][2];
    #pragma unroll
    for (int m = 0; m < MTW; ++m)
        #pragma unroll
        for (int t = 0; t < 2; ++t)
            #pragma unroll
            for (int r = 0; r < 4; ++r) acc[m][t][r] = 0.f;

    for (int ky = 0; ky < 3; ++ky) {
        const int row = i + ky - 1;
        const bool rowok = (row >= 0) && (row < H_);
        for (int s = 0; s < KS; ++s) {
            __syncthreads();
            if (FROMF32) {
                // conv1: src plane q (s<2) / k (s>=2), 32 fp32 ch -> 3 limbs
                const float* src = (s < KS / 2) ? (const float*)in0v
                                                : (const float*)in1v;
                const int cbase = (s & (KS / 2 - 1)) * 32;
                for (int idx = tid; idx < 32 * 66; idx += 256) {
                    int ci = idx / 66, px = idx - ci * 66;
                    int col = j0 - 1 + px;
                    float v = 0.f;
                    if (rowok && col >= 0 && col < W_)
                        v = src[(size_t)(b * 64 + cbase + ci) * HW_ + row * W_ + col];
                    short h, m, l;
                    split3(v, h, m, l);
                    smem[px * LSTR + ci]      = h;
                    smem[px * LSTR + 32 + ci] = m;
                    smem[px * LSTR + 64 + ci] = l;
                }
            } else {
                // packed 3-limb feat [p][limb*CIN + ci], 8B chunks
                const short* src = (const short*)in0v
                                 + (size_t)b * HW_ * (3 * CIN);
                for (int idx = tid; idx < 66 * 24; idx += 256) {
                    int px = idx / 24, r = idx - px * 24;
                    int limb = r >> 3, dq = r & 7;
                    int col = j0 - 1 + px;
                    unsigned long long v = 0;
                    if (rowok && col >= 0 && col < W_)
                        v = *(const unsigned long long*)(src
                              + (size_t)(row * W_ + col) * (3 * CIN)
                              + limb * CIN + s * 32 + dq * 4);
                    *(unsigned long long*)(&smem[px * LSTR + limb * 32 + dq * 4]) = v;
                }
            }
            __syncthreads();

            #pragma unroll
            for (int kx = 0; kx < 3; ++kx) {
                const int kk = ky * 3 + kx;
                short8 bh[2], bm[2], bl[2];
                #pragma unroll
                for (int t2 = 0; t2 < 2; ++t2) {
                    const int t = wn * 2 + t2;
                    const short* bp = &smem[(t * 16 + nn + kx) * LSTR + quad * 8];
                    bh[t2] = *(const short8*)bp;
                    bm[t2] = *(const short8*)(bp + 32);
                    bl[t2] = *(const short8*)(bp + 64);
                }
                #pragma unroll
                for (int m = 0; m < MTW; ++m) {
                    const short* ap = pw
                        + ((size_t)(((mt0 + m) * 9 + kk) * KS + s)) * 1536
                        + lane * 8;
                    short8 ah = *(const short8*)ap;
                    short8 am = *(const short8*)(ap + 512);
                    short8 al = *(const short8*)(ap + 1024);
                    #pragma unroll
                    for (int t2 = 0; t2 < 2; ++t2) {
                        acc[m][t2] = __builtin_amdgcn_mfma_f32_16x16x32_bf16(ah, bh[t2], acc[m][t2], 0, 0, 0);
                        acc[m][t2] = __builtin_amdgcn_mfma_f32_16x16x32_bf16(ah, bm[t2], acc[m][t2], 0, 0, 0);
                        acc[m][t2] = __builtin_amdgcn_mfma_f32_16x16x32_bf16(am, bh[t2], acc[m][t2], 0, 0, 0);
                        acc[m][t2] = __builtin_amdgcn_mfma_f32_16x16x32_bf16(am, bm[t2], acc[m][t2], 0, 0, 0);
                        acc[m][t2] = __builtin_amdgcn_mfma_f32_16x16x32_bf16(ah, bl[t2], acc[m][t2], 0, 0, 0);
                        acc[m][t2] = __builtin_amdgcn_mfma_f32_16x16x32_bf16(al, bh[t2], acc[m][t2], 0, 0, 0);
                    }
                }
            }
        }
    }

    // epilogue: C/D layout col(=px)=lane&15, row(=co)=quad*4+reg (verified m89)
    #pragma unroll
    for (int m = 0; m < MTW; ++m) {
        const int co0 = (mt0 + m) * 16 + quad * 4;
        #pragma unroll
        for (int t2 = 0; t2 < 2; ++t2) {
            const int t = wn * 2 + t2;
            const int p = i * W_ + j0 + t * 16 + nn;
            if (OUTMODE == 0) {
                short* feat = (short*)outv;
                short4v hv, mv, lv;
                #pragma unroll
                for (int r = 0; r < 4; ++r) {
                    float x = acc[m][t2][r] + bias[co0 + r];
                    if (LRELU) x = (x >= 0.f) ? x : 0.1f * x;
                    short h, mm, l;
                    split3(x, h, mm, l);
                    hv[r] = h; mv[r] = mm; lv[r] = l;
                }
                short* dp = feat + ((size_t)b * HW_ + p) * 192 + co0;
                *(short4v*)dp         = hv;
                *(short4v*)(dp + 64)  = mv;
                *(short4v*)(dp + 128) = lv;
            } else {
                if (co0 < 216) {
                    float* om = (float*)outv;
                    float4v v;
                    #pragma unroll
                    for (int r = 0; r < 4; ++r)
                        v[r] = acc[m][t2][r] + bias[co0 + r];
                    *(float4v*)(om + ((size_t)b * HW_ + p) * 216 + co0) = v;
                }
            }
        }
    }
}

// ---------------------------------------------------------------------------
// fused deformable sampling + top-2 attention (om NHWC [p][216])
// ---------------------------------------------------------------------------
__global__ __launch_bounds__(256) void sampler_k(
    const float* __restrict__ query, const float* __restrict__ kT,
    const float* __restrict__ vT, const float* __restrict__ om,
    float* __restrict__ out_w, float* __restrict__ out_v)
{
    const int lane = threadIdx.x & 63;
    const int wid  = threadIdx.x >> 6;
    const int P    = blockIdx.x * 4 + wid;
    const int b    = (P >= HW_) ? 1 : 0;
    const int p    = P - b * HW_;
    const int i    = p / W_;
    const int j    = p - i * W_;
    const int c    = lane;
    const int g    = lane >> 3;

    const float qc   = query[(size_t)(b * C_ + c) * HW_ + p];
    const float* omb = om + ((size_t)b * HW_ + p) * 216;

    float offy[9], offx[9], mk[9];
    #pragma unroll
    for (int n = 0; n < 9; ++n) {
        offy[n] = omb[g * 9 + n];
        offx[n] = omb[72 + g * 9 + n];
        float mv = omb[144 + g * 9 + n];
        mk[n] = 1.f / (1.f + expf(-mv));
    }

    const float* kpl = kT + (size_t)b * HW_ * 64;
    float kv[9], rel[9];
    #pragma unroll
    for (int n = 0; n < 9; ++n) {
        float ys = (float)i + (float)(n / 3 - 1) + offy[n];
        float xs = (float)j + (float)(n % 3 - 1) + offx[n];
        kv[n]  = bilin_nhwc(kpl, ys, xs, c) * mk[n];
        rel[n] = wave_sum(kv[n] * qc);
    }

    int n0 = 0; float v0 = rel[0];
    #pragma unroll
    for (int n = 1; n < 9; ++n) { if (rel[n] > v0) { v0 = rel[n]; n0 = n; } }
    int n1 = -1; float v1 = -1e30f;
    #pragma unroll
    for (int n = 0; n < 9; ++n) { if (n != n0 && rel[n] > v1) { v1 = rel[n]; n1 = n; } }

    float e1  = expf(v1 - v0);
    float inv = 1.f / (1.f + e1);
    float c0 = inv, c1 = e1 * inv;

    float kv0 = 0, kv1 = 0, oy0 = 0, ox0 = 0, m0 = 0, oy1 = 0, ox1 = 0, m1 = 0;
    #pragma unroll
    for (int n = 0; n < 9; ++n) {
        if (n == n0) { kv0 = kv[n]; oy0 = offy[n]; ox0 = offx[n]; m0 = mk[n]; }
        if (n == n1) { kv1 = kv[n]; oy1 = offy[n]; ox1 = offx[n]; m1 = mk[n]; }
    }

    float kupd = c0 * kv0 + c1 * kv1;
    float wsum = wave_sum(qc * kupd);
    if (lane == 0) out_w[(size_t)b * HW_ + p] = wsum;

    const float* vpl = vT + (size_t)b * HW_ * 64;
    float ys0 = (float)i + (float)(n0 / 3 - 1) + oy0;
    float xs0 = (float)j + (float)(n0 % 3 - 1) + ox0;
    float ys1 = (float)i + (float)(n1 / 3 - 1) + oy1;
    float xs1 = (float)j + (float)(n1 % 3 - 1) + ox1;
    float vv0 = bilin_nhwc(vpl, ys0, xs0, c) * m0;
    float vv1 = bilin_nhwc(vpl, ys1, xs1, c) * m1;
    out_v[(size_t)(b * C_ + c) * HW_ + p] = c0 * vv0 + c1 * vv1;
}

// ---------------------------------------------------------------------------
extern "C" void kernel_launch(void* const* d_in, const int* in_sizes, int n_in,
                              void* d_out, int out_size, void* d_ws, size_t ws_size,
                              hipStream_t stream)
{
    const float* query = (const float*)d_in[0];
    const float* key   = (const float*)d_in[1];
    const float* value = (const float*)d_in[2];
    const float* w1    = (const float*)d_in[3];
    const float* b1    = (const float*)d_in[4];
    const float* w2    = (const float*)d_in[5];
    const float* b2    = (const float*)d_in[6];
    const float* wom   = (const float*)d_in[7];
    const float* bom   = (const float*)d_in[8];
    float* out = (float*)d_out;

    // Liveness-packed workspace, TOTAL = 101,449,728 B (proven size).
    // Stages: prep_w(s1) conv1(s3) conv2(s4) conv_om(s5) nchw(s6) sampler(s7).
    //   f1   @0          +28,311,552   live s3-s4
    //   om   @0          +63,700,992   live s5-s7   (over dead f1)
    //   f2   @63,700,992 +28,311,552   live s4-s5
    //   kT   @63,700,992 +18,874,368   live s6-s7   (over dead f2)
    //   vT   @82,575,360 +18,874,368   live s6-s7   (over dead f2/pw tail)
    //   pwom @92,012,544 +774,144      live s1-s5   (under vT: vT written s6)
    //   pw1  @92,786,688 +442,368      live s1-s3
    //   pw2  @93,229,056 +221,184      live s1-s4
    char* ws = (char*)d_ws;
    short* f1  = (short*)(ws);
    float* om  = (float*)(ws);
    short* f2  = (short*)(ws + 63700992);
    float* kT  = (float*)(ws + 63700992);
    float* vT  = (float*)(ws + 82575360);
    short* pwom= (short*)(ws + 92012544);
    short* pw1 = (short*)(ws + 92786688);
    short* pw2 = (short*)(ws + 93229056);

    prep_w_k<<<936, 256, 0, stream>>>(w1, w2, wom, pw1, pw2, pwom);

    conv_mfma<128, 4,  true,  0, true ><<<1152, 256, 0, stream>>>(query, key, pw1, b1, (void*)f1);
    conv_mfma<64,  4,  true,  0, false><<<1152, 256, 0, stream>>>(f1, nullptr, pw2, b2, (void*)f2);
    conv_mfma<64,  14, false, 1, false><<<1152, 256, 0, stream>>>(f2, nullptr, pwom, bom, (void*)om);

    nchw_to_nhwc<<<dim3(576, B_, 2), 256, 0, stream>>>(key, value, kT, vT);

    float* out_w = out;
    float* out_v = out + (size_t)B_ * HW_;
    sampler_k<<<(B_ * HW_) / 4, 256, 0, stream>>>(query, kT, vT, om, out_w, out_v);
}

// Round 9
// 433.953 us; speedup vs baseline: 2.8932x; 1.1759x over previous
//
#include <hip/hip_runtime.h>
#include <math.h>

#define H_  192
#define W_  192
#define HW_ (192 * 192)
#define B_  2
#define C_  64

typedef __attribute__((ext_vector_type(8))) short short8;
typedef __attribute__((ext_vector_type(4))) short short4v;
typedef __attribute__((ext_vector_type(4))) float float4v;

// ---------------------------------------------------------------------------
// bf16 helpers (RNE)
// ---------------------------------------------------------------------------
__device__ __forceinline__ unsigned short f2bf(float f) {
    unsigned u = __float_as_uint(f);
    u += 0x7FFFu + ((u >> 16) & 1u);
    return (unsigned short)(u >> 16);
}
__device__ __forceinline__ float bf2f(unsigned short h) {
    return __uint_as_float((unsigned)h << 16);
}
// 3-limb split: x = h + m + l, each bf16; residual ~2^-27 * |x|
__device__ __forceinline__ void split3(float x, short& h, short& m, short& l) {
    unsigned short hh = f2bf(x);
    float r1 = x - bf2f(hh);
    unsigned short mm = f2bf(r1);
    float r2 = r1 - bf2f(mm);
    unsigned short ll = f2bf(r2);
    h = (short)hh; m = (short)mm; l = (short)ll;
}

// ---------------------------------------------------------------------------
// bilinear sample helpers on NHWC fp32 planes ([HW][64] one batch).
// bilin_dot: dot of the 4-channel bilinear sample with q4 (for rel scores).
// bilin_v4 : the 4-channel bilinear sample itself (for value output).
// Semantics match reference exactly: corner weight zeroed when OOB,
// gather index clamped.
// ---------------------------------------------------------------------------
__device__ __forceinline__ float bilin_dot(const float* __restrict__ pl,
                                           float ys, float xs, int c4,
                                           float4v q4) {
    float y0 = floorf(ys), x0 = floorf(xs);
    float fy = ys - y0, fx = xs - x0;
    int iy = (int)y0, ix = (int)x0;
    float acc = 0.f;
    #pragma unroll
    for (int dy = 0; dy < 2; ++dy) {
        #pragma unroll
        for (int dx = 0; dx < 2; ++dx) {
            int yy = iy + dy, xx = ix + dx;
            float wgt = (dy ? fy : 1.f - fy) * (dx ? fx : 1.f - fx);
            bool valid = (yy >= 0) && (yy < H_) && (xx >= 0) && (xx < W_);
            int yc = min(max(yy, 0), H_ - 1);
            int xc = min(max(xx, 0), W_ - 1);
            const float4v v = *(const float4v*)(pl + (size_t)(yc * W_ + xc) * 64 + c4);
            float d = v[0] * q4[0] + v[1] * q4[1] + v[2] * q4[2] + v[3] * q4[3];
            acc += valid ? wgt * d : 0.f;
        }
    }
    return acc;
}
__device__ __forceinline__ float4v bilin_v4(const float* __restrict__ pl,
                                            float ys, float xs, int c4) {
    float y0 = floorf(ys), x0 = floorf(xs);
    float fy = ys - y0, fx = xs - x0;
    int iy = (int)y0, ix = (int)x0;
    float4v acc;
    acc[0] = acc[1] = acc[2] = acc[3] = 0.f;
    #pragma unroll
    for (int dy = 0; dy < 2; ++dy) {
        #pragma unroll
        for (int dx = 0; dx < 2; ++dx) {
            int yy = iy + dy, xx = ix + dx;
            float wgt = (dy ? fy : 1.f - fy) * (dx ? fx : 1.f - fx);
            bool valid = (yy >= 0) && (yy < H_) && (xx >= 0) && (xx < W_);
            float wz = valid ? wgt : 0.f;
            int yc = min(max(yy, 0), H_ - 1);
            int xc = min(max(xx, 0), W_ - 1);
            const float4v v = *(const float4v*)(pl + (size_t)(yc * W_ + xc) * 64 + c4);
            #pragma unroll
            for (int r = 0; r < 4; ++r) acc[r] += wz * v[r];
        }
    }
    return acc;
}

// ---------------------------------------------------------------------------
// weight pack: OIHW fp32 -> MFMA-fragment-ordered bf16 3-limb.
// frag elems: [frag][h:512][m:512][l:512] (stride 1536)
// frag = (mt*9 + kykx)*KS + s ; co = mt*16+(lane&15) ; ci = s*32+(lane>>4)*8+j
// pw1: 144 frags (MT=4,KS=4,CIN=128); pw2: 72 (MT=4,KS=2); pwom: 252 (MT=14,KS=2)
// ---------------------------------------------------------------------------
__global__ __launch_bounds__(256) void prep_w_k(
    const float* __restrict__ w1, const float* __restrict__ w2,
    const float* __restrict__ wom,
    short* __restrict__ pw1, short* __restrict__ pw2, short* __restrict__ pwom)
{
    int idx = blockIdx.x * 256 + threadIdx.x;
    int arr;
    if (idx < 144 * 512) { arr = 0; }
    else if (idx < (144 + 72) * 512) { arr = 1; idx -= 144 * 512; }
    else if (idx < (144 + 72 + 252) * 512) { arr = 2; idx -= (144 + 72) * 512; }
    else return;
    int frag = idx >> 9, within = idx & 511;
    int lane = within >> 3, j = within & 7;
    int KS   = (arr == 0) ? 4 : 2;
    int mt   = frag / (9 * KS);
    int rem  = frag % (9 * KS);
    int kk   = rem / KS;
    int s    = rem % KS;
    int co   = mt * 16 + (lane & 15);
    int c    = s * 32 + (lane >> 4) * 8 + j;
    float v = 0.f;
    if (arr == 0)      v = w1[(co * 128 + c) * 9 + kk];
    else if (arr == 1) v = w2[(co * 64 + c) * 9 + kk];
    else if (co < 216) v = wom[(co * 64 + c) * 9 + kk];
    short h, m, l;
    split3(v, h, m, l);
    short* dst = (arr == 0) ? pw1 : (arr == 1) ? pw2 : pwom;
    size_t base = (size_t)frag * 1536 + lane * 8 + j;
    dst[base]        = h;
    dst[base + 512]  = m;
    dst[base + 1024] = l;
}

// ---------------------------------------------------------------------------
// NCHW -> NHWC fp32 transpose for key/value (sampler inputs)
// ---------------------------------------------------------------------------
__global__ __launch_bounds__(256) void nchw_to_nhwc(
    const float* __restrict__ key, const float* __restrict__ value,
    float* __restrict__ kT, float* __restrict__ vT)
{
    __shared__ float sm[64][65];
    const int tid = threadIdx.x;
    const int p0  = blockIdx.x * 64;
    const int b   = blockIdx.y;
    const float* src = blockIdx.z ? value : key;
    float*       dst = blockIdx.z ? vT    : kT;
    const int pp = tid & 63;
    const int r0 = tid >> 6;
    #pragma unroll
    for (int c = r0; c < 64; c += 4)
        sm[c][pp] = src[(size_t)(b * 64 + c) * HW_ + p0 + pp];
    __syncthreads();
    const int cc = tid & 63;
    #pragma unroll
    for (int pw = r0; pw < 64; pw += 4)
        dst[((size_t)b * HW_ + p0 + pw) * 64 + cc] = sm[cc][pw];
}

// ---------------------------------------------------------------------------
// implicit-GEMM 3x3 SAME conv via mfma_f32_16x16x32_bf16, 3-limb / 6-pass.
// Block = 256 threads (4 waves), wave (wh, wn) = (M-half, N-half) quadrant.
// N = 64 px of one image row; LDS stages 66 px x 32 ci x 3 limbs per (ky,s).
// 1D grid 1152, XCD-affine swizzle: xcd=flat&7 owns a 48-row band of one
// batch -> ky-halo rows + pw weights stay in that XCD's L2.
// FROMF32 (conv1): stages fp32 NCHW query/key with on-the-fly split3.
// OUTMODE 0: packed feat 3-limb [p][h64][m64][l64] (+lrelu)
// OUTMODE 1: om NHWC fp32 [p][216] (COUT=216 in M=224)
// ---------------------------------------------------------------------------
template<int CIN, int MT, bool LRELU, int OUTMODE, bool FROMF32>
__global__ __launch_bounds__(256) void conv_mfma(
    const void* __restrict__ in0v, const void* __restrict__ in1v,
    const short* __restrict__ pw, const float* __restrict__ bias,
    void* __restrict__ outv)
{
    constexpr int KS   = CIN / 32;
    constexpr int MTW  = MT / 2;               // M-tiles per wave
    constexpr int LSTR = 104;                  // shorts per px: 3*32 + 8 pad
    __shared__ __align__(16) short smem[66 * LSTR];

    const int tid  = threadIdx.x;
    const int lane = tid & 63;
    const int w    = tid >> 6;                 // 0..3
    const int wh   = w & 1;                    // M-half
    const int wn   = w >> 1;                   // N-half
    const int quad = lane >> 4;
    const int nn   = lane & 15;

    // XCD-affine swizzle (1152 blocks = 8 xcd * 144)
    const int flat = blockIdx.x;
    const int xcd  = flat & 7;
    const int cc_  = flat >> 3;                // 0..143
    const int b    = xcd >> 2;                 // batch
    const int r4   = xcd & 3;
    const int i    = r4 * 48 + cc_ / 3;        // row
    const int j0   = (cc_ % 3) * 64;
    const int mt0  = wh * MTW;

    float4v acc[MTW][2];
    #pragma unroll
    for (int m = 0; m < MTW; ++m)
        #pragma unroll
        for (int t = 0; t < 2; ++t)
            #pragma unroll
            for (int r = 0; r < 4; ++r) acc[m][t][r] = 0.f;

    for (int ky = 0; ky < 3; ++ky) {
        const int row = i + ky - 1;
        const bool rowok = (row >= 0) && (row < H_);
        for (int s = 0; s < KS; ++s) {
            __syncthreads();
            if (FROMF32) {
                // conv1: src plane q (s<2) / k (s>=2), 32 fp32 ch -> 3 limbs
                const float* src = (s < KS / 2) ? (const float*)in0v
                                                : (const float*)in1v;
                const int cbase = (s & (KS / 2 - 1)) * 32;
                for (int idx = tid; idx < 32 * 66; idx += 256) {
                    int ci = idx / 66, px = idx - ci * 66;
                    int col = j0 - 1 + px;
                    float v = 0.f;
                    if (rowok && col >= 0 && col < W_)
                        v = src[(size_t)(b * 64 + cbase + ci) * HW_ + row * W_ + col];
                    short h, m, l;
                    split3(v, h, m, l);
                    smem[px * LSTR + ci]      = h;
                    smem[px * LSTR + 32 + ci] = m;
                    smem[px * LSTR + 64 + ci] = l;
                }
            } else {
                // packed 3-limb feat [p][limb*CIN + ci], 8B chunks
                const short* src = (const short*)in0v
                                 + (size_t)b * HW_ * (3 * CIN);
                for (int idx = tid; idx < 66 * 24; idx += 256) {
                    int px = idx / 24, r = idx - px * 24;
                    int limb = r >> 3, dq = r & 7;
                    int col = j0 - 1 + px;
                    unsigned long long v = 0;
                    if (rowok && col >= 0 && col < W_)
                        v = *(const unsigned long long*)(src
                              + (size_t)(row * W_ + col) * (3 * CIN)
                              + limb * CIN + s * 32 + dq * 4);
                    *(unsigned long long*)(&smem[px * LSTR + limb * 32 + dq * 4]) = v;
                }
            }
            __syncthreads();

            #pragma unroll
            for (int kx = 0; kx < 3; ++kx) {
                const int kk = ky * 3 + kx;
                short8 bh[2], bm[2], bl[2];
                #pragma unroll
                for (int t2 = 0; t2 < 2; ++t2) {
                    const int t = wn * 2 + t2;
                    const short* bp = &smem[(t * 16 + nn + kx) * LSTR + quad * 8];
                    bh[t2] = *(const short8*)bp;
                    bm[t2] = *(const short8*)(bp + 32);
                    bl[t2] = *(const short8*)(bp + 64);
                }
                #pragma unroll
                for (int m = 0; m < MTW; ++m) {
                    const short* ap = pw
                        + ((size_t)(((mt0 + m) * 9 + kk) * KS + s)) * 1536
                        + lane * 8;
                    short8 ah = *(const short8*)ap;
                    short8 am = *(const short8*)(ap + 512);
                    short8 al = *(const short8*)(ap + 1024);
                    #pragma unroll
                    for (int t2 = 0; t2 < 2; ++t2) {
                        acc[m][t2] = __builtin_amdgcn_mfma_f32_16x16x32_bf16(ah, bh[t2], acc[m][t2], 0, 0, 0);
                        acc[m][t2] = __builtin_amdgcn_mfma_f32_16x16x32_bf16(ah, bm[t2], acc[m][t2], 0, 0, 0);
                        acc[m][t2] = __builtin_amdgcn_mfma_f32_16x16x32_bf16(am, bh[t2], acc[m][t2], 0, 0, 0);
                        acc[m][t2] = __builtin_amdgcn_mfma_f32_16x16x32_bf16(am, bm[t2], acc[m][t2], 0, 0, 0);
                        acc[m][t2] = __builtin_amdgcn_mfma_f32_16x16x32_bf16(ah, bl[t2], acc[m][t2], 0, 0, 0);
                        acc[m][t2] = __builtin_amdgcn_mfma_f32_16x16x32_bf16(al, bh[t2], acc[m][t2], 0, 0, 0);
                    }
                }
            }
        }
    }

    // epilogue: C/D layout col(=px)=lane&15, row(=co)=quad*4+reg (verified m89)
    #pragma unroll
    for (int m = 0; m < MTW; ++m) {
        const int co0 = (mt0 + m) * 16 + quad * 4;
        #pragma unroll
        for (int t2 = 0; t2 < 2; ++t2) {
            const int t = wn * 2 + t2;
            const int p = i * W_ + j0 + t * 16 + nn;
            if (OUTMODE == 0) {
                short* feat = (short*)outv;
                short4v hv, mv, lv;
                #pragma unroll
                for (int r = 0; r < 4; ++r) {
                    float x = acc[m][t2][r] + bias[co0 + r];
                    if (LRELU) x = (x >= 0.f) ? x : 0.1f * x;
                    short h, mm, l;
                    split3(x, h, mm, l);
                    hv[r] = h; mv[r] = mm; lv[r] = l;
                }
                short* dp = feat + ((size_t)b * HW_ + p) * 192 + co0;
                *(short4v*)dp         = hv;
                *(short4v*)(dp + 64)  = mv;
                *(short4v*)(dp + 128) = lv;
            } else {
                if (co0 < 216) {
                    float* om = (float*)outv;
                    float4v v;
                    #pragma unroll
                    for (int r = 0; r < 4; ++r)
                        v[r] = acc[m][t2][r] + bias[co0 + r];
                    *(float4v*)(om + ((size_t)b * HW_ + p) * 216 + co0) = v;
                }
            }
        }
    }
}

// ---------------------------------------------------------------------------
// fused deformable sampling + top-2 attention, v2.
// Block = 256 thr = 4 waves; wave covers 4 px; lane = px_sub(2b) x cl(4b);
// lane cl handles channels 4cl..4cl+3 (float4 on NHWC kT/vT) of pixel
// pblk + w*4 + px_sub. q staged in LDS (coalesced). rel reduced over the
// 16 lanes of a pixel (butterfly, bitwise-identical on all lanes).
// weight = c0*rel[n0] + c1*rel[n1] (algebraic identity - no second pass).
// ---------------------------------------------------------------------------
__global__ __launch_bounds__(256) void sampler_k(
    const float* __restrict__ query, const float* __restrict__ kT,
    const float* __restrict__ vT, const float* __restrict__ om,
    float* __restrict__ out_w, float* __restrict__ out_v)
{
    __shared__ float sq[16 * 68];
    const int tid  = threadIdx.x;
    const int bb   = blockIdx.x;
    const int b    = bb / 2304;
    const int pblk = (bb - b * 2304) * 16;

    // stage q[16 px][64 ch] -> LDS, fully coalesced (64B per channel row)
    #pragma unroll
    for (int k = 0; k < 4; ++k) {
        int idx = tid + k * 256;           // 0..1023
        int c   = idx >> 4;
        int px  = idx & 15;
        sq[px * 68 + c] = query[(size_t)(b * 64 + c) * HW_ + pblk + px];
    }
    __syncthreads();

    const int lane   = tid & 63;
    const int w      = tid >> 6;
    const int px_sub = lane >> 4;
    const int cl     = lane & 15;
    const int c4     = cl * 4;
    const int g      = cl >> 1;
    const int p      = pblk + w * 4 + px_sub;
    const int i      = p / W_;
    const int j      = p - i * W_;

    const float4v q4 = *(const float4v*)&sq[(w * 4 + px_sub) * 68 + c4];

    const float* omb = om + ((size_t)b * HW_ + p) * 216;
    float offy[9], offx[9], mk[9];
    #pragma unroll
    for (int n = 0; n < 9; ++n) {
        offy[n] = omb[g * 9 + n];
        offx[n] = omb[72 + g * 9 + n];
        float mv = omb[144 + g * 9 + n];
        mk[n] = 1.f / (1.f + expf(-mv));
    }

    const float* kpl = kT + (size_t)b * HW_ * 64;
    float rel[9];
    #pragma unroll
    for (int n = 0; n < 9; ++n) {
        float ys = (float)i + (float)(n / 3 - 1) + offy[n];
        float xs = (float)j + (float)(n % 3 - 1) + offx[n];
        float d = bilin_dot(kpl, ys, xs, c4, q4) * mk[n];
        #pragma unroll
        for (int off = 1; off < 16; off <<= 1)
            d += __shfl_xor(d, off, 64);
        rel[n] = d;
    }

    // top-2 with lax.top_k tie semantics (first occurrence of max wins)
    int n0 = 0; float v0 = rel[0];
    #pragma unroll
    for (int n = 1; n < 9; ++n) { if (rel[n] > v0) { v0 = rel[n]; n0 = n; } }
    int n1 = -1; float v1 = -1e30f;
    #pragma unroll
    for (int n = 0; n < 9; ++n) { if (n != n0 && rel[n] > v1) { v1 = rel[n]; n1 = n; } }

    float e1  = expf(v1 - v0);
    float inv = 1.f / (1.f + e1);
    float c0 = inv, c1 = e1 * inv;

    // weight = q . k_upd = c0*rel[n0] + c1*rel[n1]
    if (cl == 0) out_w[(size_t)b * HW_ + p] = c0 * v0 + c1 * v1;

    // gather offsets/mask for the two selected taps (cndmask chains)
    float oy0 = 0, ox0 = 0, m0 = 0, oy1 = 0, ox1 = 0, m1 = 0;
    #pragma unroll
    for (int n = 0; n < 9; ++n) {
        if (n == n0) { oy0 = offy[n]; ox0 = offx[n]; m0 = mk[n]; }
        if (n == n1) { oy1 = offy[n]; ox1 = offx[n]; m1 = mk[n]; }
    }

    const float* vpl = vT + (size_t)b * HW_ * 64;
    float ys0 = (float)i + (float)(n0 / 3 - 1) + oy0;
    float xs0 = (float)j + (float)(n0 % 3 - 1) + ox0;
    float ys1 = (float)i + (float)(n1 / 3 - 1) + oy1;
    float xs1 = (float)j + (float)(n1 % 3 - 1) + ox1;
    float4v vv0 = bilin_v4(vpl, ys0, xs0, c4);
    float4v vv1 = bilin_v4(vpl, ys1, xs1, c4);
    float w0 = c0 * m0, w1s = c1 * m1;
    #pragma unroll
    for (int r = 0; r < 4; ++r)
        out_v[(size_t)(b * C_ + c4 + r) * HW_ + p] = w0 * vv0[r] + w1s * vv1[r];
}

// ---------------------------------------------------------------------------
extern "C" void kernel_launch(void* const* d_in, const int* in_sizes, int n_in,
                              void* d_out, int out_size, void* d_ws, size_t ws_size,
                              hipStream_t stream)
{
    const float* query = (const float*)d_in[0];
    const float* key   = (const float*)d_in[1];
    const float* value = (const float*)d_in[2];
    const float* w1    = (const float*)d_in[3];
    const float* b1    = (const float*)d_in[4];
    const float* w2    = (const float*)d_in[5];
    const float* b2    = (const float*)d_in[6];
    const float* wom   = (const float*)d_in[7];
    const float* bom   = (const float*)d_in[8];
    float* out = (float*)d_out;

    // Liveness-packed workspace, TOTAL = 101,449,728 B (proven size).
    // Stages: prep_w(s1) conv1(s3) conv2(s4) conv_om(s5) nchw(s6) sampler(s7).
    //   f1   @0          +28,311,552   live s3-s4
    //   om   @0          +63,700,992   live s5-s7   (over dead f1)
    //   f2   @63,700,992 +28,311,552   live s4-s5
    //   kT   @63,700,992 +18,874,368   live s6-s7   (over dead f2)
    //   vT   @82,575,360 +18,874,368   live s6-s7   (over dead f2/pw tail)
    //   pwom @92,012,544 +774,144      live s1-s5   (under vT: vT written s6)
    //   pw1  @92,786,688 +442,368      live s1-s3
    //   pw2  @93,229,056 +221,184      live s1-s4
    char* ws = (char*)d_ws;
    short* f1  = (short*)(ws);
    float* om  = (float*)(ws);
    short* f2  = (short*)(ws + 63700992);
    float* kT  = (float*)(ws + 63700992);
    float* vT  = (float*)(ws + 82575360);
    short* pwom= (short*)(ws + 92012544);
    short* pw1 = (short*)(ws + 92786688);
    short* pw2 = (short*)(ws + 93229056);

    prep_w_k<<<936, 256, 0, stream>>>(w1, w2, wom, pw1, pw2, pwom);

    conv_mfma<128, 4,  true,  0, true ><<<1152, 256, 0, stream>>>(query, key, pw1, b1, (void*)f1);
    conv_mfma<64,  4,  true,  0, false><<<1152, 256, 0, stream>>>(f1, nullptr, pw2, b2, (void*)f2);
    conv_mfma<64,  14, false, 1, false><<<1152, 256, 0, stream>>>(f2, nullptr, pwom, bom, (void*)om);

    nchw_to_nhwc<<<dim3(576, B_, 2), 256, 0, stream>>>(key, value, kT, vT);

    float* out_w = out;
    float* out_v = out + (size_t)B_ * HW_;
    sampler_k<<<(B_ * HW_) / 16, 256, 0, stream>>>(query, kT, vT, om, out_w, out_v);
}